// Round 2
// baseline (6530.344 us; speedup 1.0000x reference)
//
#include <hip/hip_runtime.h>
#include <cstdint>

#define NN0 80000
#define NE 1280000
#define MMB_GRID 2048
#define EB 2048          // elems per block in edge sort (NE/EB = 625 exact)
#define ENB 625
#define HPSTRIDE 20480   // pool hist slice stride (256 digits * up to 80 blocks)
#define SYNC_STRIDE 1024 // per-persistent-kernel sync slice (flags + gen)

static inline int cdiv(int a, int b){ return (a+b-1)/b; }

// ======================= custom grid barrier =======================
// flags[b] monotonically increasing per-block arrival counters; gen is the
// release word. Co-residency guaranteed by hipLaunchCooperativeKernel.
#define ASCOPE __HIP_MEMORY_SCOPE_AGENT

__device__ __forceinline__ void gbar(int* flags, int* gen, int target){
  __syncthreads();                      // drains this block's stores (vmcnt)
  if (threadIdx.x == 0){
    __threadfence();                    // agent release for bulk data
    __hip_atomic_store(&flags[blockIdx.x], target, __ATOMIC_RELEASE, ASCOPE);
  }
  if (blockIdx.x == 0){
    int nb = gridDim.x;
    for (int i = threadIdx.x; i < nb; i += 256){
      while (__hip_atomic_load(&flags[i], __ATOMIC_ACQUIRE, ASCOPE) < target)
        __builtin_amdgcn_s_sleep(1);
    }
    __syncthreads();
    if (threadIdx.x == 0){
      __threadfence();
      __hip_atomic_store(gen, target, __ATOMIC_RELEASE, ASCOPE);
    }
  } else {
    if (threadIdx.x == 0){
      while (__hip_atomic_load(gen, __ATOMIC_ACQUIRE, ASCOPE) < target)
        __builtin_amdgcn_s_sleep(1);
      __threadfence();                  // agent acquire for bulk data
    }
  }
  __syncthreads();
}

__global__ void k_init(int* sync, int n){
  for (int i = threadIdx.x; i < n; i += 256) sync[i] = 0;
}

// ======================= plain (non-cooperative) conv kernels =======================
// (verbatim from the 741us baseline — bit-identical stats/partials)

__global__ void k_conv64(const int* __restrict__ rp, const int* __restrict__ col,
                         const float* __restrict__ dinv, const float* __restrict__ x,
                         const float* __restrict__ W, float* __restrict__ out,
                         float* __restrict__ part, int n){
  __shared__ float yl[4][64];
  __shared__ float ls[64], lq[64];
  int lane = threadIdx.x & 63, w = threadIdx.x >> 6;
  if (threadIdx.x < 64){ ls[threadIdx.x] = 0.f; lq[threadIdx.x] = 0.f; }
  __syncthreads();
  float sa = 0.f, sq = 0.f;
  int wid = blockIdx.x*4 + w, nw = gridDim.x*4;
  for (int i = wid; i < n; i += nw){
    int beg = rp[i], end = rp[i+1];
    float di = dinv[i];
    float y = 0.f;
    int j = beg;
    for (; j + 4 <= end; j += 4){
      int s0 = col[j], s1 = col[j+1], s2 = col[j+2], s3 = col[j+3];
      float y0 = dinv[s0]*x[s0*64+lane];
      float y1 = dinv[s1]*x[s1*64+lane];
      float y2 = dinv[s2]*x[s2*64+lane];
      float y3 = dinv[s3]*x[s3*64+lane];
      y += (y0+y1) + (y2+y3);
    }
    for (; j < end; j++){ int s = col[j]; y += dinv[s]*x[s*64+lane]; }
    y = di*y + 2.f*di*di*x[i*64+lane];
    yl[w][lane] = y;
    float acc = 0.f;
    #pragma unroll
    for (int k2 = 0; k2 < 64; k2++)
      acc += yl[w][k2]*W[k2*64+lane];
    out[i*64+lane] = acc;
    sa += acc; sq += acc*acc;
  }
  atomicAdd(&ls[lane], sa); atomicAdd(&lq[lane], sq);
  __syncthreads();
  if (threadIdx.x < 128)
    part[blockIdx.x*128 + threadIdx.x] =
      (threadIdx.x < 64) ? ls[threadIdx.x] : lq[threadIdx.x-64];
}

__global__ void k_conv3(const int* __restrict__ rp, const int* __restrict__ col,
                        const float* __restrict__ dinv, const float* __restrict__ x,
                        const float* __restrict__ W, float* __restrict__ out,
                        float* __restrict__ part, int n){
  __shared__ float ls[64], lq[64];
  int lane = threadIdx.x & 63, w = threadIdx.x >> 6;
  if (threadIdx.x < 64){ ls[threadIdx.x] = 0.f; lq[threadIdx.x] = 0.f; }
  __syncthreads();
  float wf0 = W[lane], wf1 = W[64+lane], wf2 = W[128+lane];
  float sa = 0.f, sq = 0.f;
  int wid = blockIdx.x*4 + w, nw = gridDim.x*4;
  for (int i = wid; i < n; i += nw){
    int beg = rp[i], end = rp[i+1];
    float a0 = 0.f, a1 = 0.f, a2 = 0.f;
    for (int j = beg + lane; j < end; j += 64){
      int s2 = col[j];
      float ds = dinv[s2];
      a0 += ds*x[s2*3+0]; a1 += ds*x[s2*3+1]; a2 += ds*x[s2*3+2];
    }
    for (int o = 32; o > 0; o >>= 1){
      a0 += __shfl_xor(a0, o); a1 += __shfl_xor(a1, o); a2 += __shfl_xor(a2, o);
    }
    float di = dinv[i];
    float sl = 2.f*di*di;
    a0 = di*a0 + sl*x[i*3+0];
    a1 = di*a1 + sl*x[i*3+1];
    a2 = di*a2 + sl*x[i*3+2];
    float s = a0*wf0 + a1*wf1 + a2*wf2;
    out[i*64+lane] = s; sa += s; sq += s*s;
  }
  atomicAdd(&ls[lane], sa); atomicAdd(&lq[lane], sq);
  __syncthreads();
  if (threadIdx.x < 128)
    part[blockIdx.x*128 + threadIdx.x] =
      (threadIdx.x < 64) ? ls[threadIdx.x] : lq[threadIdx.x-64];
}

// ======================= device phases =======================

static __device__ void stats_phase(const float* part, float* stats){
  int lane = threadIdx.x & 63, w = threadIdx.x >> 6;
  for (int c = blockIdx.x*4 + w; c < 128; c += gridDim.x*4){
    float s = 0.f;
    for (int b = lane; b < MMB_GRID; b += 64) s += part[b*128 + c];
    for (int o = 32; o > 0; o >>= 1) s += __shfl_xor(s, o);
    if (lane == 0) stats[c] = s;
  }
}

// ---- edge radix sort phases (6-bit digits, 3 passes) ----
static __device__ void ehist_phase(const int* key, int* hist, int shift,
                                   int* z, int zn){
  for (int i = blockIdx.x*blockDim.x + threadIdx.x; i < zn; i += gridDim.x*blockDim.x)
    z[i] = 0;
  __shared__ int lh[64];
  for (int vb = blockIdx.x; vb < ENB; vb += gridDim.x){
    if (threadIdx.x < 64) lh[threadIdx.x] = 0;
    __syncthreads();
    int base = vb*EB + threadIdx.x;
    #pragma unroll
    for (int u = 0; u < 8; u++)
      atomicAdd(&lh[(key[base + u*256] >> shift) & 63], 1);
    __syncthreads();
    if (threadIdx.x < 64) hist[threadIdx.x*ENB + vb] = lh[threadIdx.x];
    __syncthreads();
  }
}

// scatter computes its own dbase from the raw histogram; optionally builds the
// next pass's histogram via global atomics (counts are deterministic).
static __device__ void escatter_phase(const int* keyin, const int* valin,
                                      int* keyout, int* valout,
                                      const int* hist, int shift,
                                      int* nexthist, int nextshift){
  __shared__ int dbase[64], run[64], wcnt[4][64];
  __shared__ int ptot[4][64], ppre[4][64];
  int t = threadIdx.x, lane = t & 63, w = t >> 6;
  for (int vb = blockIdx.x; vb < ENB; vb += gridDim.x){
    {
      int b0 = w*157, b1 = b0 + 157; if (b1 > ENB) b1 = ENB;
      int pre = 0, tot = 0;
      for (int b = b0; b < b1; b++){
        int v = hist[lane*ENB + b];
        if (b < vb) pre += v;
        tot += v;
      }
      ptot[w][lane] = tot; ppre[w][lane] = pre;
    }
    __syncthreads();
    if (t < 64){
      int tt = ptot[0][t]+ptot[1][t]+ptot[2][t]+ptot[3][t];
      int pp = ppre[0][t]+ppre[1][t]+ppre[2][t]+ppre[3][t];
      int xv = tt;
      for (int o = 1; o < 64; o <<= 1){
        int y = __shfl_up(xv, o);
        if (lane >= o) xv += y;
      }
      dbase[t] = (xv - tt) + pp;
      run[t] = 0;
    }
    __syncthreads();
    for (int u = 0; u < 8; u++){
      if (t < 64){ wcnt[0][t]=0; wcnt[1][t]=0; wcnt[2][t]=0; wcnt[3][t]=0; }
      __syncthreads();
      int g = vb*EB + u*256 + t;
      int kk = keyin[g], vv = valin[g];
      int d = (kk >> shift) & 63;
      unsigned long long m = ~0ull;
      #pragma unroll
      for (int b = 0; b < 6; b++){
        unsigned long long bal = __ballot((d >> b) & 1);
        m &= ((d >> b) & 1) ? bal : ~bal;
      }
      int rnk = __popcll(m & ((1ull << lane) - 1ull));
      if (rnk == 0) wcnt[w][d] = __popcll(m);
      __syncthreads();
      int off2 = run[d] + rnk;
      for (int w2 = 0; w2 < w; w2++) off2 += wcnt[w2][d];
      int pos = dbase[d] + off2;
      keyout[pos] = kk; valout[pos] = vv;
      if (nexthist)
        atomicAdd(&nexthist[((kk >> nextshift) & 63)*ENB + (pos >> 11)], 1);
      __syncthreads();
      if (t < 64) run[t] += wcnt[0][t] + wcnt[1][t] + wcnt[2][t] + wcnt[3][t];
      __syncthreads();
    }
  }
}

static __device__ void rp_search_phase(const int* skey, int* rp,
                                       float* dA, float* dB, int n){
  for (int i = blockIdx.x*blockDim.x + threadIdx.x; i < n; i += gridDim.x*blockDim.x){
    int lo = 0, hi = NE;
    while (lo < hi){ int mid = (lo+hi)>>1; if (skey[mid] < i) lo = mid+1; else hi = mid; }
    int a2 = lo;
    lo = a2; hi = NE;
    while (lo < hi){ int mid = (lo+hi)>>1; if (skey[mid] < i+1) lo = mid+1; else hi = mid; }
    int b2 = lo;
    rp[i] = a2;
    if (i == n-1) rp[n] = NE;
    float deg = (float)(b2 - a2);
    dA[i] = 1.0f/sqrtf(deg + 2.f);
    dB[i] = 1.0f/sqrtf(deg + 1.f);
  }
}

// ---- scans for child-CSR ----
static __device__ void scan_part_phase(const int* in, int* bsumv, int n2){
  __shared__ int ws[256];
  int nb = (n2 + 2047) >> 11;
  for (int vb = blockIdx.x; vb < nb; vb += gridDim.x){
    int base = vb*2048 + threadIdx.x*8;
    int s = 0;
    #pragma unroll
    for (int u = 0; u < 8; u++){ int i = base+u; if (i < n2) s += in[i]; }
    ws[threadIdx.x] = s; __syncthreads();
    for (int st = 128; st > 0; st >>= 1){
      if (threadIdx.x < st) ws[threadIdx.x] += ws[threadIdx.x+st];
      __syncthreads();
    }
    if (threadIdx.x == 0) bsumv[vb] = ws[0];
    __syncthreads();
  }
}

static __device__ void scan_fin_rp_phase(const int* in, const int* bsumv,
                                         int* rp, float* dinvv, int n){
  __shared__ int bws[256]; __shared__ int ws[256];
  int nb = (n + 2047) >> 11;
  int t = threadIdx.x;
  for (int vb = blockIdx.x; vb < nb; vb += gridDim.x){
    bws[t] = (t < nb) ? bsumv[t] : 0; __syncthreads();
    for (int st = 1; st < 256; st <<= 1){
      int a = (t >= st) ? bws[t-st] : 0; __syncthreads();
      bws[t] += a; __syncthreads();
    }
    int blockoff = (vb == 0) ? 0 : bws[vb-1];
    int base = vb*2048 + t*8;
    int v[8]; int s = 0;
    #pragma unroll
    for (int u = 0; u < 8; u++){ int i = base+u; v[u] = (i < n) ? in[i] : 0; s += v[u]; }
    ws[t] = s; __syncthreads();
    for (int st = 1; st < 256; st <<= 1){
      int a = (t >= st) ? ws[t-st] : 0; __syncthreads();
      ws[t] += a; __syncthreads();
    }
    int off = blockoff + ws[t] - s;
    #pragma unroll
    for (int u = 0; u < 8; u++){
      int i = base+u;
      if (i < n){
        rp[i] = off; off += v[u];
        dinvv[i] = 1.0f/sqrtf((float)v[u] + 2.f);
        if (i == n-1) rp[n] = off;
      }
    }
    __syncthreads();
  }
}

// ---- pool phases ----
static __device__ void bnrelu_score_phase(float* x, const float* stats,
    const float* gamma, const float* beta, const float* pw,
    float* score, unsigned* key, int* idx, int n, int P,
    int* z, int zn){
  for (int i = blockIdx.x*blockDim.x + threadIdx.x; i < zn; i += gridDim.x*blockDim.x)
    z[i] = 0;
  int lane = threadIdx.x & 63, w = threadIdx.x >> 6;
  int wid = blockIdx.x*4 + w, nw = gridDim.x*4;
  float inv_n = 1.f/(float)n;
  float mu = stats[lane]*inv_n;
  float var = stats[64+lane]*inv_n - mu*mu;
  float gs = gamma[lane]*(1.f/sqrtf(var+1e-5f));
  float bt = beta[lane];
  float pv = pw[lane];
  float q = pv*pv;
  for (int o = 32; o > 0; o >>= 1) q += __shfl_xor(q, o);
  float qn = 1.f/sqrtf(q);
  for (int i = wid; i < n; i += nw){
    float v = fmaxf(gs*(x[i*64+lane]-mu)+bt, 0.f);
    x[i*64+lane] = v;
    float s = v*pv;
    for (int o = 32; o > 0; o >>= 1) s += __shfl_xor(s, o);
    if (lane == 0){
      float sc = fmaxf(s*qn, 0.f);
      score[i] = sc; key[i] = ~__float_as_uint(sc); idx[i] = i;
    }
  }
  for (int g = n + wid; g < P; g += nw)
    if (lane == 0){ key[g] = 0xFFFFFFFFu; idx[g] = 0; }
}

static __device__ void radix_hist_phase(const unsigned* key, int* hist, int shift, int nblk){
  __shared__ int lh[256];
  for (int vb = blockIdx.x; vb < nblk; vb += gridDim.x){
    lh[threadIdx.x] = 0; __syncthreads();
    int base = vb*1024 + threadIdx.x;
    #pragma unroll
    for (int u = 0; u < 4; u++){
      unsigned d = (key[base + u*256] >> shift) & 255u;
      atomicAdd(&lh[d], 1);
    }
    __syncthreads();
    hist[threadIdx.x*nblk + vb] = lh[threadIdx.x];
    __syncthreads();
  }
}

static __device__ void radix_scatter_phase(const unsigned* keyin, const int* idxin,
    unsigned* keyout, int* idxout, const int* hist, int shift, int nblk,
    int* nexthist, int nextshift){
  __shared__ int dbase[256], run[256], sc[256];
  __shared__ int wcnt4[4][256];
  int t = threadIdx.x, lane = t & 63, w = t >> 6;
  for (int vb = blockIdx.x; vb < nblk; vb += gridDim.x){
    int pre = 0, tot = 0;
    for (int b = 0; b < nblk; b++){
      int v = hist[t*nblk + b];
      if (b < vb) pre += v;
      tot += v;
    }
    sc[t] = tot; __syncthreads();
    for (int st = 1; st < 256; st <<= 1){
      int a = (t >= st) ? sc[t-st] : 0; __syncthreads();
      sc[t] += a; __syncthreads();
    }
    dbase[t] = sc[t] - tot + pre;
    run[t] = 0;
    for (int u = 0; u < 4; u++){
      wcnt4[0][t] = 0; wcnt4[1][t] = 0; wcnt4[2][t] = 0; wcnt4[3][t] = 0;
      __syncthreads();
      int g = vb*1024 + u*256 + t;
      unsigned kk = keyin[g]; int id = idxin[g];
      unsigned d = (kk >> shift) & 255u;
      unsigned long long m = ~0ull;
      #pragma unroll
      for (int b = 0; b < 8; b++){
        unsigned long long bal = __ballot((d >> b) & 1u);
        m &= ((d >> b) & 1u) ? bal : ~bal;
      }
      int rnk = __popcll(m & ((1ull << lane) - 1ull));
      if (rnk == 0) wcnt4[w][d] = __popcll(m);
      __syncthreads();
      int off2 = run[d] + rnk;
      for (int w2 = 0; w2 < w; w2++) off2 += wcnt4[w2][d];
      int pos = dbase[d] + off2;
      keyout[pos] = kk; idxout[pos] = id;
      if (nexthist)
        atomicAdd(&nexthist[((kk >> nextshift) & 255u)*nblk + (pos >> 10)], 1);
      __syncthreads();
      run[t] += wcnt4[0][t] + wcnt4[1][t] + wcnt4[2][t] + wcnt4[3][t];
      __syncthreads();
    }
  }
}

static __device__ void select_gather_phase(const int* idxs, const float* x,
    const float* score, int* perm, int* mapv, float* xk, int n, int k){
  int total = k*64;
  for (int t = blockIdx.x*blockDim.x + threadIdx.x; t < total; t += gridDim.x*blockDim.x){
    if (t < n){
      int i = idxs[t];
      mapv[i] = (t < k) ? t : -1;
      if (t < k) perm[t] = i;
    }
    int r = t >> 6, f = t & 63;
    int i = idxs[r];
    xk[t] = x[i*64+f]*score[i];
  }
}

static __device__ void hist_mapped_phase(const int* rp_p, const int* col_p,
                                         const int* mapv, int* indeg, int np){
  for (int d = blockIdx.x*blockDim.x + threadIdx.x; d < np; d += gridDim.x*blockDim.x){
    int md = mapv[d];
    if (md < 0) continue;
    int c = 0, e = rp_p[d+1];
    int j = rp_p[d];
    for (; j + 4 <= e; j += 4){
      int c0 = (mapv[col_p[j]]   >= 0);
      int c1 = (mapv[col_p[j+1]] >= 0);
      int c2 = (mapv[col_p[j+2]] >= 0);
      int c3 = (mapv[col_p[j+3]] >= 0);
      c += (c0+c1) + (c2+c3);
    }
    for (; j < e; j++) if (mapv[col_p[j]] >= 0) c++;
    indeg[md] = c;
  }
}

static __device__ void scatter_mapped_phase(const int* rp_p, const int* col_p,
    const int* mapv, const int* rp_c, int* col_c, int np){
  for (int d = blockIdx.x*blockDim.x + threadIdx.x; d < np; d += gridDim.x*blockDim.x){
    int md = mapv[d];
    if (md < 0) continue;
    int pos = rp_c[md], e = rp_p[d+1];
    int j = rp_p[d];
    for (; j + 4 <= e; j += 4){
      int m0 = mapv[col_p[j]], m1 = mapv[col_p[j+1]];
      int m2 = mapv[col_p[j+2]], m3 = mapv[col_p[j+3]];
      if (m0 >= 0) col_c[pos++] = m0;
      if (m1 >= 0) col_c[pos++] = m1;
      if (m2 >= 0) col_c[pos++] = m2;
      if (m3 >= 0) col_c[pos++] = m3;
    }
    for (; j < e; j++){
      int ms = mapv[col_p[j]];
      if (ms >= 0) col_c[pos++] = ms;
    }
  }
}

// ======================= persistent kernels (custom barrier) =======================

struct EdgeArgs {
  const int* dst0; const int* src0;
  int* ek1; int* ev1; int* ek2; int* ev2; int* col0;
  int* eh0; int* eh1; int* eh2;
  int* rp0; float* dinv0; float* dinv0f;
  int* flags; int* gen;
};

__global__ __launch_bounds__(256, 4) void k_edges_p(EdgeArgs a){
  int bt = 0;
  // h0 (also zeroes eh1,eh2 which are built by atomics in s0/s1)
  ehist_phase(a.dst0, a.eh0, 0, a.eh1, 2*64*ENB);            gbar(a.flags,a.gen,++bt);
  escatter_phase(a.dst0, a.src0, a.ek1, a.ev1, a.eh0, 0,  a.eh1, 6);  gbar(a.flags,a.gen,++bt);
  escatter_phase(a.ek1, a.ev1, a.ek2, a.ev2, a.eh1, 6,  a.eh2, 12);   gbar(a.flags,a.gen,++bt);
  escatter_phase(a.ek2, a.ev2, a.ek1, a.col0, a.eh2, 12, nullptr, 0); gbar(a.flags,a.gen,++bt);
  rp_search_phase(a.ek1, a.rp0, a.dinv0, a.dinv0f, NN0);
}

struct PoolArgs {
  const float* part; float* stats;
  float* x; const float* gamma; const float* beta; const float* pw;
  float* score; unsigned* keyA; int* idxA; unsigned* keyB; int* idxB;
  int* h0; int* h1; int* h2; int* h3;
  int* perm; int* mapv; float* xk;
  const int* rp_p; const int* col_p; int* indeg; int* bsum;
  int* rp_c; int* col_c; float* dinv_c;
  int* flags; int* gen;
  int n; int k;
};

__global__ __launch_bounds__(256, 4) void k_pool_p(PoolArgs a){
  int bt = 0;
  stats_phase(a.part, a.stats);                               gbar(a.flags,a.gen,++bt);
  int nblk = (a.n + 1023) >> 10, P = nblk*1024;
  // score (also zeroes h1..h3, which are built by atomics during scatters)
  bnrelu_score_phase(a.x, a.stats, a.gamma, a.beta, a.pw, a.score,
                     a.keyA, a.idxA, a.n, P, a.h1, 3*HPSTRIDE); gbar(a.flags,a.gen,++bt);
  radix_hist_phase(a.keyA, a.h0, 0, nblk);                    gbar(a.flags,a.gen,++bt);
  radix_scatter_phase(a.keyA, a.idxA, a.keyB, a.idxB, a.h0, 0,  nblk, a.h1, 8);   gbar(a.flags,a.gen,++bt);
  radix_scatter_phase(a.keyB, a.idxB, a.keyA, a.idxA, a.h1, 8,  nblk, a.h2, 16);  gbar(a.flags,a.gen,++bt);
  radix_scatter_phase(a.keyA, a.idxA, a.keyB, a.idxB, a.h2, 16, nblk, a.h3, 24);  gbar(a.flags,a.gen,++bt);
  radix_scatter_phase(a.keyB, a.idxB, a.keyA, a.idxA, a.h3, 24, nblk, nullptr, 0);gbar(a.flags,a.gen,++bt);
  select_gather_phase(a.idxA, a.x, a.score, a.perm, a.mapv, a.xk, a.n, a.k);      gbar(a.flags,a.gen,++bt);
  hist_mapped_phase(a.rp_p, a.col_p, a.mapv, a.indeg, a.n);   gbar(a.flags,a.gen,++bt);
  scan_part_phase(a.indeg, a.bsum, a.k);                      gbar(a.flags,a.gen,++bt);
  scan_fin_rp_phase(a.indeg, a.bsum, a.rp_c, a.dinv_c, a.k);  gbar(a.flags,a.gen,++bt);
  scatter_mapped_phase(a.rp_p, a.col_p, a.mapv, a.rp_c, a.col_c, a.n);
}

struct UpArgs {
  const float* x; const float* part; float* stats;
  const float* gamma; const float* beta;
  const int* perm; float* res; int n;
  int* flags; int* gen;
};

__global__ __launch_bounds__(256, 4) void k_up_p(UpArgs a){
  int bt = 0;
  stats_phase(a.part, a.stats);                               gbar(a.flags,a.gen,++bt);
  int total = a.n*64;
  float inv_n = 1.0f/(float)a.n;
  for (int t = blockIdx.x*blockDim.x + threadIdx.x; t < total; t += gridDim.x*blockDim.x){
    int r = t >> 6, f = t & 63;
    float mu = a.stats[f]*inv_n;
    float var = a.stats[64+f]*inv_n - mu*mu;
    float v = a.gamma[f]*(a.x[t]-mu)*(1.0f/sqrtf(var+1e-5f)) + a.beta[f];
    a.res[a.perm[r]*64+f] += fmaxf(v, 0.f);
  }
}

struct FinArgs {
  const float* x; const float* W; float* h1;
  const int* rp; const int* col; const float* dinv;
  float* out; int n;
  int* flags; int* gen;
};

__global__ __launch_bounds__(256, 4) void k_fin_p(FinArgs a){
  int bt = 0;
  {
    int lane = threadIdx.x & 63, w = threadIdx.x >> 6;
    int wid = blockIdx.x*4 + w, nw = gridDim.x*4;
    float wv = a.W[lane];
    for (int i = wid; i < a.n; i += nw){
      float v = a.x[i*64+lane]*wv;
      for (int o = 32; o > 0; o >>= 1) v += __shfl_xor(v, o);
      if (lane == 0) a.h1[i] = v;
    }
  }
  gbar(a.flags,a.gen,++bt);
  for (int i = blockIdx.x*blockDim.x + threadIdx.x; i < a.n; i += gridDim.x*blockDim.x){
    int beg = a.rp[i], end = a.rp[i+1];
    float di = a.dinv[i];
    float acc = 0.f;
    int j = beg;
    for (; j + 4 <= end; j += 4){
      int s0 = a.col[j], s1 = a.col[j+1], s2 = a.col[j+2], s3 = a.col[j+3];
      float v0 = a.dinv[s0]*a.h1[s0];
      float v1 = a.dinv[s1]*a.h1[s1];
      float v2 = a.dinv[s2]*a.h1[s2];
      float v3 = a.dinv[s3]*a.h1[s3];
      acc += (v0+v1) + (v2+v3);
    }
    for (; j < end; j++) acc += a.dinv[a.col[j]]*a.h1[a.col[j]];
    float v = di*acc + di*di*a.h1[i];
    a.out[i] = 1.f/(1.f+expf(-v));
  }
}

// ======================= host =======================

extern "C" void kernel_launch(void* const* d_in, const int* in_sizes, int n_in,
                              void* d_out, int out_size, void* d_ws, size_t ws_size,
                              hipStream_t stream) {
  const float* x_in = (const float*)d_in[0];
  const int* ei = (const int*)d_in[1];
  const int* src0 = ei;
  const int* dst0 = ei + NE;
  const float* W_d[4] = {(const float*)d_in[2],(const float*)d_in[5],(const float*)d_in[8],(const float*)d_in[11]};
  const float* g_d[4] = {(const float*)d_in[3],(const float*)d_in[6],(const float*)d_in[9],(const float*)d_in[12]};
  const float* b_d[4] = {(const float*)d_in[4],(const float*)d_in[7],(const float*)d_in[10],(const float*)d_in[13]};
  const float* pw[3]  = {(const float*)d_in[14],(const float*)d_in[15],(const float*)d_in[16]};
  const float* W_u[2] = {(const float*)d_in[17],(const float*)d_in[20]};
  const float* g_u[2] = {(const float*)d_in[18],(const float*)d_in[21]};
  const float* b_u[2] = {(const float*)d_in[19],(const float*)d_in[22]};
  const float* W_out  = (const float*)d_in[23];
  float* out = (float*)d_out;

  float* base = (float*)d_ws;
  size_t off = 0;
  auto alloc = [&](size_t nf){ float* p = base + off; off += nf; return p; };
  float* x0 = alloc(5120000);
  float* x1 = alloc(2560000);
  float* x2 = alloc(1280000);
  float* x3 = alloc(640000);
  float* A  = alloc(2560000);
  int* col0 = (int*)alloc(NE);
  int* col1 = (int*)alloc(NE);
  int* col2 = (int*)alloc(NE);
  int* col3 = (int*)alloc(NE);
  int* ek1 = (int*)alloc(NE);
  int* ev1 = (int*)alloc(NE);
  int* ek2 = (int*)alloc(NE);
  int* ev2 = (int*)alloc(NE);
  int* rp0 = (int*)alloc(80001);
  int* rp1 = (int*)alloc(40001);
  int* rp2 = (int*)alloc(20001);
  int* rp3 = (int*)alloc(10001);
  int* indeg  = (int*)alloc(NN0);
  float* dinv0  = alloc(NN0);
  float* dinv0f = alloc(NN0);
  float* dinv1  = alloc(40000);
  float* dinv2  = alloc(20000);
  float* dinv3  = alloc(10000);
  float* score = alloc(NN0);
  int* mapv = (int*)alloc(NN0);
  int* p0 = (int*)alloc(40000);
  int* p1 = (int*)alloc(20000);
  int* p2 = (int*)alloc(10000);
  float* stats = alloc(128);
  float* part  = alloc(MMB_GRID*128);
  unsigned* keyA = (unsigned*)alloc(81920);
  unsigned* keyB = (unsigned*)alloc(81920);
  int* idxA = (int*)alloc(81920);
  int* idxB = (int*)alloc(81920);
  // edge hists: eh1, eh2 contiguous (zeroed together), then eh0
  int* eh1 = (int*)alloc(64*ENB);
  int* eh2 = (int*)alloc(64*ENB);
  int* eh0 = (int*)alloc(64*ENB);
  // pool hists: h1,h2,h3 contiguous (zeroed together), then h0
  int* hb = (int*)alloc(4*HPSTRIDE);
  int* h1b = hb, *h2b = hb + HPSTRIDE, *h3b = hb + 2*HPSTRIDE, *h0b = hb + 3*HPSTRIDE;
  int* bsum = (int*)alloc(256);
  int* syncb = (int*)alloc(8*SYNC_STRIDE);   // 8 slices: edges, pool x3, up x3, final
  (void)ws_size; (void)in_sizes; (void)n_in; (void)out_size;

  auto slice_flags = [&](int i){ return syncb + i*SYNC_STRIDE; };
  auto slice_gen   = [&](int i){ return syncb + i*SYNC_STRIDE + 700; };

  auto coopG = [&](const void* f, int want)->int{
    int per = 0;
    if (hipOccupancyMaxActiveBlocksPerMultiprocessor(&per, f, 256, 0) != hipSuccess || per < 1)
      per = 4;
    long mx = (long)per * 256;
    return (int)(want < mx ? want : mx);
  };

  // zero all barrier state (must precede the persistent kernels every iteration)
  k_init<<<1, 256, 0, stream>>>(syncb, 8*SYNC_STRIDE);

  // ---- level-0 CSR: fused 3-pass edge radix sort + rp/dinv (4 barriers) ----
  {
    static int G = 0; if (!G) G = coopG((const void*)k_edges_p, ENB);
    EdgeArgs ea = {dst0, src0, ek1, ev1, ek2, ev2, col0, eh0, eh1, eh2,
                   rp0, dinv0, dinv0f, slice_flags(0), slice_gen(0)};
    void* args[] = {(void*)&ea};
    hipLaunchCooperativeKernel((const void*)k_edges_p, dim3(G), dim3(256), args, 0, stream);
  }

  // ---- down path ----
  k_conv3<<<MMB_GRID, 256, 0, stream>>>(rp0, col0, dinv0, x_in, W_d[0], x0, part, NN0);

  static int Gp = 0; if (!Gp) Gp = coopG((const void*)k_pool_p, 512);
  static int Gu = 0; if (!Gu) Gu = coopG((const void*)k_up_p, 512);

  {
    PoolArgs pa = {part, stats, x0, g_d[0], b_d[0], pw[0], score, keyA, idxA, keyB, idxB,
                   h0b, h1b, h2b, h3b, p0, mapv, A, rp0, col0, indeg, bsum,
                   rp1, col1, dinv1, slice_flags(1), slice_gen(1), NN0, 40000};
    void* args[] = {(void*)&pa};
    hipLaunchCooperativeKernel((const void*)k_pool_p, dim3(Gp), dim3(256), args, 0, stream);
  }
  k_conv64<<<MMB_GRID, 256, 0, stream>>>(rp1, col1, dinv1, A, W_d[1], x1, part, 40000);

  {
    PoolArgs pa = {part, stats, x1, g_d[1], b_d[1], pw[1], score, keyA, idxA, keyB, idxB,
                   h0b, h1b, h2b, h3b, p1, mapv, A, rp1, col1, indeg, bsum,
                   rp2, col2, dinv2, slice_flags(2), slice_gen(2), 40000, 20000};
    void* args[] = {(void*)&pa};
    hipLaunchCooperativeKernel((const void*)k_pool_p, dim3(Gp), dim3(256), args, 0, stream);
  }
  k_conv64<<<MMB_GRID, 256, 0, stream>>>(rp2, col2, dinv2, A, W_d[2], x2, part, 20000);

  {
    PoolArgs pa = {part, stats, x2, g_d[2], b_d[2], pw[2], score, keyA, idxA, keyB, idxB,
                   h0b, h1b, h2b, h3b, p2, mapv, A, rp2, col2, indeg, bsum,
                   rp3, col3, dinv3, slice_flags(3), slice_gen(3), 20000, 10000};
    void* args[] = {(void*)&pa};
    hipLaunchCooperativeKernel((const void*)k_pool_p, dim3(Gp), dim3(256), args, 0, stream);
  }
  k_conv64<<<MMB_GRID, 256, 0, stream>>>(rp3, col3, dinv3, A, W_d[3], x3, part, 10000);

  // ---- up path (stats fused with BN+ReLU+scatter-add, 1 barrier each) ----
  {
    UpArgs ua = {x3, part, stats, g_d[3], b_d[3], p2, x2, 10000, slice_flags(4), slice_gen(4)};
    void* args[] = {(void*)&ua};
    hipLaunchCooperativeKernel((const void*)k_up_p, dim3(Gu), dim3(256), args, 0, stream);
  }
  k_conv64<<<MMB_GRID, 256, 0, stream>>>(rp2, col2, dinv2, x2, W_u[0], A, part, 20000);
  {
    UpArgs ua = {A, part, stats, g_u[0], b_u[0], p1, x1, 20000, slice_flags(5), slice_gen(5)};
    void* args[] = {(void*)&ua};
    hipLaunchCooperativeKernel((const void*)k_up_p, dim3(Gu), dim3(256), args, 0, stream);
  }
  k_conv64<<<MMB_GRID, 256, 0, stream>>>(rp1, col1, dinv1, x1, W_u[1], A, part, 40000);
  {
    UpArgs ua = {A, part, stats, g_u[1], b_u[1], p0, x0, 40000, slice_flags(6), slice_gen(6)};
    void* args[] = {(void*)&ua};
    hipLaunchCooperativeKernel((const void*)k_up_p, dim3(Gu), dim3(256), args, 0, stream);
  }

  // ---- final conv (fill = 1.0) fused with sigmoid (1 barrier) ----
  {
    static int Gf = 0; if (!Gf) Gf = coopG((const void*)k_fin_p, 512);
    float* h1 = score;  // reuse
    FinArgs fa = {x0, W_out, h1, rp0, col0, dinv0f, out, NN0, slice_flags(7), slice_gen(7)};
    void* args[] = {(void*)&fa};
    hipLaunchCooperativeKernel((const void*)k_fin_p, dim3(Gf), dim3(256), args, 0, stream);
  }
}

// Round 3
// 2852.336 us; speedup vs baseline: 2.2895x; 2.2895x over previous
//
#include <hip/hip_runtime.h>
#include <cstdint>

#define NN0 80000
#define NE 1280000
#define MMB_GRID 2048
#define HPSTRIDE 20480   // pool hist slice stride (256 digits * up to 80 blocks)

static inline int cdiv(int a, int b){ return (a+b-1)/b; }

// ======================= init: zero BN stats slices + level-0 indeg =======================
__global__ void k_init(float* stats6, int* indeg){
  int t = blockIdx.x*blockDim.x + threadIdx.x;
  if (t < 768) stats6[t] = 0.f;
  for (int i = t; i < NN0; i += gridDim.x*blockDim.x) indeg[i] = 0;
}

// ======================= level-0 CSR build (atomic, no sort) =======================
__global__ void k_deg0(const int* __restrict__ dst, int* __restrict__ indeg){
  for (int e = blockIdx.x*blockDim.x + threadIdx.x; e < NE; e += gridDim.x*blockDim.x)
    atomicAdd(&indeg[dst[e]], 1);
}

__global__ void k_escat0(const int* __restrict__ dst, const int* __restrict__ srcv,
                         int* __restrict__ cur, int* __restrict__ col){
  for (int e = blockIdx.x*blockDim.x + threadIdx.x; e < NE; e += gridDim.x*blockDim.x){
    int d = dst[e];
    int pos = atomicAdd(&cur[d], 1);
    col[pos] = srcv[e];
  }
}

// ======================= scans =======================
__global__ void k_scan_part(const int* __restrict__ in, int* __restrict__ bsum, int n){
  __shared__ int ws[256];
  int base = blockIdx.x*2048 + threadIdx.x*8;
  int s = 0;
  #pragma unroll
  for (int u = 0; u < 8; u++){ int i = base+u; if (i < n) s += in[i]; }
  ws[threadIdx.x] = s; __syncthreads();
  for (int st = 128; st > 0; st >>= 1){
    if (threadIdx.x < st) ws[threadIdx.x] += ws[threadIdx.x+st];
    __syncthreads();
  }
  if (threadIdx.x == 0) bsum[blockIdx.x] = ws[0];
}

// final scan: rp[0..n] (+ optional cursor copy) + dinvA (fill=2) + optional dinvB (fill=1)
__global__ void k_scan_fin_rp(const int* __restrict__ in, const int* __restrict__ bsum, int nb,
                              int* __restrict__ rp, int* __restrict__ cur,
                              float* __restrict__ dinvA, float* __restrict__ dinvB, int n){
  __shared__ int bws[256]; __shared__ int ws[256];
  int t = threadIdx.x;
  bws[t] = (t < nb) ? bsum[t] : 0; __syncthreads();
  for (int st = 1; st < 256; st <<= 1){
    int a = (t >= st) ? bws[t-st] : 0; __syncthreads();
    bws[t] += a; __syncthreads();
  }
  int blockoff = (blockIdx.x == 0) ? 0 : bws[blockIdx.x-1];
  int base = blockIdx.x*2048 + t*8;
  int v[8]; int s = 0;
  #pragma unroll
  for (int u = 0; u < 8; u++){ int i = base+u; v[u] = (i < n) ? in[i] : 0; s += v[u]; }
  ws[t] = s; __syncthreads();
  for (int st = 1; st < 256; st <<= 1){
    int a = (t >= st) ? ws[t-st] : 0; __syncthreads();
    ws[t] += a; __syncthreads();
  }
  int off = blockoff + ws[t] - s;
  #pragma unroll
  for (int u = 0; u < 8; u++){
    int i = base+u;
    if (i < n){
      rp[i] = off;
      if (cur) cur[i] = off;
      off += v[u];
      dinvA[i] = 1.0f/sqrtf((float)v[u] + 2.f);
      if (dinvB) dinvB[i] = 1.0f/sqrtf((float)v[u] + 1.f);
      if (i == n-1) rp[n] = off;
    }
  }
}

// ======================= convs (BN partials atomically added to stats slice) ===========

__global__ void k_conv64(const int* __restrict__ rp, const int* __restrict__ col,
                         const float* __restrict__ dinv, const float* __restrict__ x,
                         const float* __restrict__ W, float* __restrict__ out,
                         float* __restrict__ statsS, int* __restrict__ h0z, int nz, int n){
  for (int i = blockIdx.x*blockDim.x + threadIdx.x; i < nz; i += gridDim.x*blockDim.x)
    h0z[i] = 0;
  __shared__ float yl[4][64];
  __shared__ float ls[64], lq[64];
  int lane = threadIdx.x & 63, w = threadIdx.x >> 6;
  if (threadIdx.x < 64){ ls[threadIdx.x] = 0.f; lq[threadIdx.x] = 0.f; }
  __syncthreads();
  float sa = 0.f, sq = 0.f;
  int wid = blockIdx.x*4 + w, nw = gridDim.x*4;
  for (int i = wid; i < n; i += nw){
    int beg = rp[i], end = rp[i+1];
    float di = dinv[i];
    float y = 0.f;
    int j = beg;
    for (; j + 4 <= end; j += 4){
      int s0 = col[j], s1 = col[j+1], s2 = col[j+2], s3 = col[j+3];
      float y0 = dinv[s0]*x[s0*64+lane];
      float y1 = dinv[s1]*x[s1*64+lane];
      float y2 = dinv[s2]*x[s2*64+lane];
      float y3 = dinv[s3]*x[s3*64+lane];
      y += (y0+y1) + (y2+y3);
    }
    for (; j < end; j++){ int s = col[j]; y += dinv[s]*x[s*64+lane]; }
    y = di*y + 2.f*di*di*x[i*64+lane];
    yl[w][lane] = y;
    float acc = 0.f;
    #pragma unroll
    for (int k2 = 0; k2 < 64; k2++)
      acc += yl[w][k2]*W[k2*64+lane];
    out[i*64+lane] = acc;
    sa += acc; sq += acc*acc;
  }
  atomicAdd(&ls[lane], sa); atomicAdd(&lq[lane], sq);
  __syncthreads();
  if (threadIdx.x < 128)
    atomicAdd(&statsS[threadIdx.x],
              (threadIdx.x < 64) ? ls[threadIdx.x] : lq[threadIdx.x-64]);
}

__global__ void k_conv3(const int* __restrict__ rp, const int* __restrict__ col,
                        const float* __restrict__ dinv, const float* __restrict__ x,
                        const float* __restrict__ W, float* __restrict__ out,
                        float* __restrict__ statsS, int* __restrict__ h0z, int nz, int n){
  for (int i = blockIdx.x*blockDim.x + threadIdx.x; i < nz; i += gridDim.x*blockDim.x)
    h0z[i] = 0;
  __shared__ float ls[64], lq[64];
  int lane = threadIdx.x & 63, w = threadIdx.x >> 6;
  if (threadIdx.x < 64){ ls[threadIdx.x] = 0.f; lq[threadIdx.x] = 0.f; }
  __syncthreads();
  float wf0 = W[lane], wf1 = W[64+lane], wf2 = W[128+lane];
  float sa = 0.f, sq = 0.f;
  int wid = blockIdx.x*4 + w, nw = gridDim.x*4;
  for (int i = wid; i < n; i += nw){
    int beg = rp[i], end = rp[i+1];
    float a0 = 0.f, a1 = 0.f, a2 = 0.f;
    for (int j = beg + lane; j < end; j += 64){
      int s2 = col[j];
      float ds = dinv[s2];
      a0 += ds*x[s2*3+0]; a1 += ds*x[s2*3+1]; a2 += ds*x[s2*3+2];
    }
    for (int o = 32; o > 0; o >>= 1){
      a0 += __shfl_xor(a0, o); a1 += __shfl_xor(a1, o); a2 += __shfl_xor(a2, o);
    }
    float di = dinv[i];
    float sl = 2.f*di*di;
    a0 = di*a0 + sl*x[i*3+0];
    a1 = di*a1 + sl*x[i*3+1];
    a2 = di*a2 + sl*x[i*3+2];
    float s = a0*wf0 + a1*wf1 + a2*wf2;
    out[i*64+lane] = s; sa += s; sq += s*s;
  }
  atomicAdd(&ls[lane], sa); atomicAdd(&lq[lane], sq);
  __syncthreads();
  if (threadIdx.x < 128)
    atomicAdd(&statsS[threadIdx.x],
              (threadIdx.x < 64) ? ls[threadIdx.x] : lq[threadIdx.x-64]);
}

// ======================= pool: BN+ReLU + score + key init + pass0 hist ================
__global__ void k_pool_score(float* __restrict__ x, const float* __restrict__ stats,
                             const float* __restrict__ gamma, const float* __restrict__ beta,
                             const float* __restrict__ pw,
                             float* __restrict__ score, unsigned* __restrict__ key,
                             int* __restrict__ idx, int* __restrict__ h0,
                             int* __restrict__ hz, int n, int nblk){
  for (int i = blockIdx.x*blockDim.x + threadIdx.x; i < 3*HPSTRIDE; i += gridDim.x*blockDim.x)
    hz[i] = 0;
  int P = nblk*1024;
  int lane = threadIdx.x & 63, w = threadIdx.x >> 6;
  int wid = blockIdx.x*4 + w, nw = gridDim.x*4;
  float inv_n = 1.f/(float)n;
  float mu = stats[lane]*inv_n;
  float var = stats[64+lane]*inv_n - mu*mu;
  float gs = gamma[lane]*(1.f/sqrtf(var+1e-5f));
  float bt = beta[lane];
  float pv = pw[lane];
  float q = pv*pv;
  for (int o = 32; o > 0; o >>= 1) q += __shfl_xor(q, o);
  float qn = 1.f/sqrtf(q);
  for (int i = wid; i < n; i += nw){
    float v = fmaxf(gs*(x[i*64+lane]-mu)+bt, 0.f);
    x[i*64+lane] = v;
    float s = v*pv;
    for (int o = 32; o > 0; o >>= 1) s += __shfl_xor(s, o);
    if (lane == 0){
      float sc = fmaxf(s*qn, 0.f);
      unsigned kk = ~__float_as_uint(sc);
      score[i] = sc; key[i] = kk; idx[i] = i;
      atomicAdd(&h0[(kk & 255u)*nblk + (i >> 10)], 1);
    }
  }
  for (int g = n + wid; g < P; g += nw)
    if (lane == 0){
      key[g] = 0xFFFFFFFFu; idx[g] = 0;
      atomicAdd(&h0[255*nblk + (g >> 10)], 1);
    }
}

// ======================= radix scatter (derives dbase; builds next hist) ==============
__global__ void k_radix_scatter(const unsigned* __restrict__ keyin, const int* __restrict__ idxin,
                                unsigned* __restrict__ keyout, int* __restrict__ idxout,
                                const int* __restrict__ hist, int shift, int nblk,
                                int* __restrict__ nexthist, int nextshift){
  __shared__ int dbase[256], run[256], sc[256];
  __shared__ int wcnt[4][256];
  int t = threadIdx.x, lane = t & 63, w = t >> 6;
  int pre = 0, tot = 0;
  for (int b = 0; b < nblk; b++){
    int v = hist[t*nblk + b];
    if (b < blockIdx.x) pre += v;
    tot += v;
  }
  sc[t] = tot; __syncthreads();
  for (int st = 1; st < 256; st <<= 1){
    int a = (t >= st) ? sc[t-st] : 0; __syncthreads();
    sc[t] += a; __syncthreads();
  }
  dbase[t] = sc[t] - tot + pre;
  run[t] = 0;
  for (int u = 0; u < 4; u++){
    wcnt[0][t] = 0; wcnt[1][t] = 0; wcnt[2][t] = 0; wcnt[3][t] = 0;
    __syncthreads();
    int g = blockIdx.x*1024 + u*256 + t;
    unsigned kk = keyin[g]; int id = idxin[g];
    unsigned d = (kk >> shift) & 255u;
    unsigned long long m = ~0ull;
    #pragma unroll
    for (int b = 0; b < 8; b++){
      unsigned long long bal = __ballot((d >> b) & 1u);
      m &= ((d >> b) & 1u) ? bal : ~bal;
    }
    int rnk = __popcll(m & ((1ull << lane) - 1ull));
    if (rnk == 0) wcnt[w][d] = __popcll(m);
    __syncthreads();
    int off2 = run[d] + rnk;
    for (int w2 = 0; w2 < w; w2++) off2 += wcnt[w2][d];
    int pos = dbase[d] + off2;
    keyout[pos] = kk; idxout[pos] = id;
    if (nexthist)
      atomicAdd(&nexthist[((kk >> nextshift) & 255u)*nblk + (pos >> 10)], 1);
    __syncthreads();
    run[t] += wcnt[0][t] + wcnt[1][t] + wcnt[2][t] + wcnt[3][t];
    __syncthreads();
  }
}

// ======================= select + gather-scale =======================
__global__ void k_select_gather(const int* __restrict__ idxs, const float* __restrict__ x,
                                const float* __restrict__ score, int* __restrict__ perm,
                                int* __restrict__ mapv, float* __restrict__ xk, int n, int k){
  int t = blockIdx.x*blockDim.x + threadIdx.x;
  if (t < n){
    int i = idxs[t];
    mapv[i] = (t < k) ? t : -1;
    if (t < k) perm[t] = i;
  }
  if (t < k*64){
    int r = t >> 6, f = t & 63;
    int i = idxs[r];
    xk[t] = x[i*64+f]*score[i];
  }
}

// ======================= child CSR from parent CSR + injective mapping ================
__global__ void k_hist_mapped(const int* __restrict__ rp_p, const int* __restrict__ col_p,
                              const int* __restrict__ mapv, int* __restrict__ indeg, int np){
  int d = blockIdx.x*blockDim.x + threadIdx.x;
  if (d >= np) return;
  int md = mapv[d];
  if (md < 0) return;
  int c = 0, e = rp_p[d+1];
  int j = rp_p[d];
  for (; j + 4 <= e; j += 4){
    int c0 = (mapv[col_p[j]]   >= 0);
    int c1 = (mapv[col_p[j+1]] >= 0);
    int c2 = (mapv[col_p[j+2]] >= 0);
    int c3 = (mapv[col_p[j+3]] >= 0);
    c += (c0+c1) + (c2+c3);
  }
  for (; j < e; j++) if (mapv[col_p[j]] >= 0) c++;
  indeg[md] = c;
}

__global__ void k_scatter_mapped(const int* __restrict__ rp_p, const int* __restrict__ col_p,
                                 const int* __restrict__ mapv, const int* __restrict__ rp_c,
                                 int* __restrict__ col_c, int np){
  int d = blockIdx.x*blockDim.x + threadIdx.x;
  if (d >= np) return;
  int md = mapv[d];
  if (md < 0) return;
  int pos = rp_c[md], e = rp_p[d+1];
  int j = rp_p[d];
  for (; j + 4 <= e; j += 4){
    int m0 = mapv[col_p[j]], m1 = mapv[col_p[j+1]];
    int m2 = mapv[col_p[j+2]], m3 = mapv[col_p[j+3]];
    if (m0 >= 0) col_c[pos++] = m0;
    if (m1 >= 0) col_c[pos++] = m1;
    if (m2 >= 0) col_c[pos++] = m2;
    if (m3 >= 0) col_c[pos++] = m3;
  }
  for (; j < e; j++){
    int ms = mapv[col_p[j]];
    if (ms >= 0) col_c[pos++] = ms;
  }
}

// ======================= up-path BN+ReLU + scatter-add =======================
__global__ void k_bnrelu_scatter(const float* __restrict__ x, const float* __restrict__ stats,
                                 const float* __restrict__ gamma, const float* __restrict__ beta,
                                 const int* __restrict__ perm, float* __restrict__ res, int n){
  int t = blockIdx.x*blockDim.x + threadIdx.x;
  if (t >= n*64) return;
  int r = t >> 6, f = t & 63;
  float inv_n = 1.0f/(float)n;
  float mu = stats[f]*inv_n;
  float var = stats[64+f]*inv_n - mu*mu;
  float v = gamma[f]*(x[t]-mu)*(1.0f/sqrtf(var+1e-5f)) + beta[f];
  res[perm[r]*64+f] += fmaxf(v, 0.f);
}

// ======================= final conv =======================
__global__ void k_matvec(const float* __restrict__ x, const float* __restrict__ W,
                         float* __restrict__ h1, int n){
  int lane = threadIdx.x & 63, w = threadIdx.x >> 6;
  int wid = blockIdx.x*4 + w, nw = gridDim.x*4;
  float wv = W[lane];
  for (int i = wid; i < n; i += nw){
    float v = x[i*64+lane]*wv;
    for (int o = 32; o > 0; o >>= 1) v += __shfl_xor(v, o);
    if (lane == 0) h1[i] = v;
  }
}

__global__ void k_gather_sig(const int* __restrict__ rp, const int* __restrict__ col,
                             const float* __restrict__ dinv, const float* __restrict__ h1,
                             float* __restrict__ out, int n){
  int i = blockIdx.x*blockDim.x + threadIdx.x;
  if (i >= n) return;
  int beg = rp[i], end = rp[i+1];
  float di = dinv[i];
  float acc = 0.f;
  int j = beg;
  for (; j + 4 <= end; j += 4){
    int s0 = col[j], s1 = col[j+1], s2 = col[j+2], s3 = col[j+3];
    float v0 = dinv[s0]*h1[s0];
    float v1 = dinv[s1]*h1[s1];
    float v2 = dinv[s2]*h1[s2];
    float v3 = dinv[s3]*h1[s3];
    acc += (v0+v1) + (v2+v3);
  }
  for (; j < end; j++) acc += dinv[col[j]]*h1[col[j]];
  float v = di*acc + di*di*h1[i];
  out[i] = 1.f/(1.f+expf(-v));
}

// ======================= host =======================

extern "C" void kernel_launch(void* const* d_in, const int* in_sizes, int n_in,
                              void* d_out, int out_size, void* d_ws, size_t ws_size,
                              hipStream_t stream) {
  const float* x_in = (const float*)d_in[0];
  const int* ei = (const int*)d_in[1];
  const int* src0 = ei;
  const int* dst0 = ei + NE;
  const float* W_d[4] = {(const float*)d_in[2],(const float*)d_in[5],(const float*)d_in[8],(const float*)d_in[11]};
  const float* g_d[4] = {(const float*)d_in[3],(const float*)d_in[6],(const float*)d_in[9],(const float*)d_in[12]};
  const float* b_d[4] = {(const float*)d_in[4],(const float*)d_in[7],(const float*)d_in[10],(const float*)d_in[13]};
  const float* pw[3]  = {(const float*)d_in[14],(const float*)d_in[15],(const float*)d_in[16]};
  const float* W_u[2] = {(const float*)d_in[17],(const float*)d_in[20]};
  const float* g_u[2] = {(const float*)d_in[18],(const float*)d_in[21]};
  const float* b_u[2] = {(const float*)d_in[19],(const float*)d_in[22]};
  const float* W_out  = (const float*)d_in[23];
  float* out = (float*)d_out;

  float* base = (float*)d_ws;
  size_t off = 0;
  auto alloc = [&](size_t nf){ float* p = base + off; off += nf; return p; };
  float* x0 = alloc(5120000);
  float* x1 = alloc(2560000);
  float* x2 = alloc(1280000);
  float* x3 = alloc(640000);
  float* A  = alloc(2560000);
  int* col0 = (int*)alloc(NE);
  int* col1 = (int*)alloc(NE);
  int* col2 = (int*)alloc(NE);
  int* col3 = (int*)alloc(NE);
  int* rp0 = (int*)alloc(80001);
  int* rp1 = (int*)alloc(40001);
  int* rp2 = (int*)alloc(20001);
  int* rp3 = (int*)alloc(10001);
  int* cur0 = (int*)alloc(NN0);
  int* indeg  = (int*)alloc(NN0);
  float* dinv0  = alloc(NN0);
  float* dinv0f = alloc(NN0);
  float* dinv1  = alloc(40000);
  float* dinv2  = alloc(20000);
  float* dinv3  = alloc(10000);
  float* score = alloc(NN0);
  int* mapv = (int*)alloc(NN0);
  int* p0 = (int*)alloc(40000);
  int* p1 = (int*)alloc(20000);
  int* p2 = (int*)alloc(10000);
  float* stats6 = alloc(768);          // 6 slices x 128 (conv3,d1,d2,d3,u0,u1)
  unsigned* keyA = (unsigned*)alloc(81920);
  unsigned* keyB = (unsigned*)alloc(81920);
  int* idxA = (int*)alloc(81920);
  int* idxB = (int*)alloc(81920);
  int* hb = (int*)alloc(4*HPSTRIDE);   // h1,h2,h3 contiguous (zeroed together), then h0
  int* h1b = hb, *h2b = hb + HPSTRIDE, *h3b = hb + 2*HPSTRIDE, *h0b = hb + 3*HPSTRIDE;
  int* bsum = (int*)alloc(256);
  (void)ws_size; (void)in_sizes; (void)n_in; (void)out_size;

  const int B = 256;
  auto S = [&](int i){ return stats6 + i*128; };

  // ---- init + level-0 CSR (atomic build; neighbor order arbitrary, fp-tolerable) ----
  k_init<<<cdiv(NN0,B), B, 0, stream>>>(stats6, indeg);
  k_deg0<<<1024, B, 0, stream>>>(dst0, indeg);
  k_scan_part<<<cdiv(NN0,2048), B, 0, stream>>>(indeg, bsum, NN0);
  k_scan_fin_rp<<<cdiv(NN0,2048), B, 0, stream>>>(indeg, bsum, cdiv(NN0,2048),
                                                  rp0, cur0, dinv0, dinv0f, NN0);
  k_escat0<<<1024, B, 0, stream>>>(dst0, src0, cur0, col0);

  auto pool = [&](float* xb, const float* st, const float* gm, const float* bt,
                  const float* pwv, int n, int k, int* pm){
    int nblk = cdiv(n, 1024);
    k_pool_score<<<1024, B, 0, stream>>>(xb, st, gm, bt, pwv, score, keyA, idxA,
                                         h0b, h1b, n, nblk);
    k_radix_scatter<<<nblk, B, 0, stream>>>(keyA, idxA, keyB, idxB, h0b, 0,  nblk, h1b, 8);
    k_radix_scatter<<<nblk, B, 0, stream>>>(keyB, idxB, keyA, idxA, h1b, 8,  nblk, h2b, 16);
    k_radix_scatter<<<nblk, B, 0, stream>>>(keyA, idxA, keyB, idxB, h2b, 16, nblk, h3b, 24);
    k_radix_scatter<<<nblk, B, 0, stream>>>(keyB, idxB, keyA, idxA, h3b, 24, nblk, nullptr, 0);
    k_select_gather<<<cdiv(k*64,B), B, 0, stream>>>(idxA, xb, score, pm, mapv, A, n, k);
  };

  auto csr_mapped = [&](const int* rp_p, const int* col_p, int np, int nc,
                        int* rp_c, int* col_c, float* dv){
    k_hist_mapped<<<cdiv(np,B), B, 0, stream>>>(rp_p, col_p, mapv, indeg, np);
    k_scan_part<<<cdiv(nc,2048), B, 0, stream>>>(indeg, bsum, nc);
    k_scan_fin_rp<<<cdiv(nc,2048), B, 0, stream>>>(indeg, bsum, cdiv(nc,2048),
                                                   rp_c, nullptr, dv, nullptr, nc);
    k_scatter_mapped<<<cdiv(np,B), B, 0, stream>>>(rp_p, col_p, mapv, rp_c, col_c, np);
  };

  // ---- down path ----
  k_conv3<<<MMB_GRID, B, 0, stream>>>(rp0, col0, dinv0, x_in, W_d[0], x0, S(0), h0b, HPSTRIDE, NN0);
  pool(x0, S(0), g_d[0], b_d[0], pw[0], NN0, 40000, p0);
  csr_mapped(rp0, col0, NN0, 40000, rp1, col1, dinv1);

  k_conv64<<<MMB_GRID, B, 0, stream>>>(rp1, col1, dinv1, A, W_d[1], x1, S(1), h0b, HPSTRIDE, 40000);
  pool(x1, S(1), g_d[1], b_d[1], pw[1], 40000, 20000, p1);
  csr_mapped(rp1, col1, 40000, 20000, rp2, col2, dinv2);

  k_conv64<<<MMB_GRID, B, 0, stream>>>(rp2, col2, dinv2, A, W_d[2], x2, S(2), h0b, HPSTRIDE, 20000);
  pool(x2, S(2), g_d[2], b_d[2], pw[2], 20000, 10000, p2);
  csr_mapped(rp2, col2, 20000, 10000, rp3, col3, dinv3);

  k_conv64<<<MMB_GRID, B, 0, stream>>>(rp3, col3, dinv3, A, W_d[3], x3, S(3), nullptr, 0, 10000);

  // ---- up path (BN+ReLU fused into the skip-connection scatter-add) ----
  k_bnrelu_scatter<<<cdiv(10000*64,B), B, 0, stream>>>(x3, S(3), g_d[3], b_d[3], p2, x2, 10000);
  k_conv64<<<MMB_GRID, B, 0, stream>>>(rp2, col2, dinv2, x2, W_u[0], A, S(4), nullptr, 0, 20000);
  k_bnrelu_scatter<<<cdiv(20000*64,B), B, 0, stream>>>(A, S(4), g_u[0], b_u[0], p1, x1, 20000);
  k_conv64<<<MMB_GRID, B, 0, stream>>>(rp1, col1, dinv1, x1, W_u[1], A, S(5), nullptr, 0, 40000);
  k_bnrelu_scatter<<<cdiv(40000*64,B), B, 0, stream>>>(A, S(5), g_u[1], b_u[1], p0, x0, 40000);

  // ---- final conv (fill = 1.0) fused with sigmoid ----
  float* h1 = score;  // reuse
  k_matvec<<<512, B, 0, stream>>>(x0, W_out, h1, NN0);
  k_gather_sig<<<cdiv(NN0,B), B, 0, stream>>>(rp0, col0, dinv0f, h1, out, NN0);
}

// Round 4
// 2041.690 us; speedup vs baseline: 3.1985x; 1.3970x over previous
//
#include <hip/hip_runtime.h>
#include <cstdint>

#define NN0 80000
#define NE 1280000
#define MMB_GRID 2048

static inline int cdiv(int a, int b){ return (a+b-1)/b; }

// ======================= level-0 CSR build (atomic, random-target) =======================
__global__ void k_deg0(const int* __restrict__ dst, int* __restrict__ indeg){
  for (int e = blockIdx.x*blockDim.x + threadIdx.x; e < NE; e += gridDim.x*blockDim.x)
    atomicAdd(&indeg[dst[e]], 1);
}

__global__ void k_escat0(const int* __restrict__ dst, const int* __restrict__ srcv,
                         int* __restrict__ cur, int* __restrict__ col){
  for (int e = blockIdx.x*blockDim.x + threadIdx.x; e < NE; e += gridDim.x*blockDim.x){
    int d = dst[e];
    int pos = atomicAdd(&cur[d], 1);
    col[pos] = srcv[e];
  }
}

// ======================= fused single-dispatch scan =======================
// Each block redundantly computes its prefix by summing in[0 .. blockIdx*2048)
// (reads are L2-resident; nb <= 40). Emits rp[0..n], optional cursor copy,
// dinvA (fill=2), optional dinvB (fill=1).
__global__ void k_scan_rp(const int* __restrict__ in, int* __restrict__ rp,
                          int* __restrict__ cur, float* __restrict__ dA,
                          float* __restrict__ dB, int n){
  __shared__ int ws[256];
  int t = threadIdx.x;
  int pre = blockIdx.x*2048;
  int s = 0;
  for (int i = t; i < pre; i += 256) s += in[i];
  ws[t] = s; __syncthreads();
  for (int st = 128; st > 0; st >>= 1){
    if (t < st) ws[t] += ws[t+st];
    __syncthreads();
  }
  int blockoff = ws[0];
  __syncthreads();
  int base = pre + t*8;
  int v[8]; int ls = 0;
  #pragma unroll
  for (int u = 0; u < 8; u++){ int i = base+u; v[u] = (i < n) ? in[i] : 0; ls += v[u]; }
  ws[t] = ls; __syncthreads();
  for (int st = 1; st < 256; st <<= 1){
    int a = (t >= st) ? ws[t-st] : 0; __syncthreads();
    ws[t] += a; __syncthreads();
  }
  int off = blockoff + ws[t] - ls;
  #pragma unroll
  for (int u = 0; u < 8; u++){
    int i = base+u;
    if (i < n){
      rp[i] = off;
      if (cur) cur[i] = off;
      off += v[u];
      dA[i] = 1.0f/sqrtf((float)v[u] + 2.f);
      if (dB) dB[i] = 1.0f/sqrtf((float)v[u] + 1.f);
      if (i == n-1) rp[n] = off;
    }
  }
}

// ======================= last-block stats reduction (bit-identical to r0) ============
__device__ __forceinline__ void conv_stats_tail(const float* __restrict__ part,
                                                float* __restrict__ stats,
                                                int* __restrict__ done){
  __shared__ int amLast;
  __syncthreads();                     // all part writes of this block issued
  if (threadIdx.x == 0){
    __threadfence();                   // make part visible device-wide
    int c = atomicAdd(done, 1);
    amLast = (c == (int)gridDim.x - 1);
  }
  __syncthreads();
  if (amLast){
    __threadfence();                   // acquire: invalidate caches before reads
    int lane = threadIdx.x & 63, w = threadIdx.x >> 6;
    for (int c = w; c < 128; c += 4){
      float s = 0.f;
      for (int b = lane; b < MMB_GRID; b += 64) s += part[b*128 + c];
      for (int o = 32; o > 0; o >>= 1) s += __shfl_xor(s, o);
      if (lane == 0) stats[c] = s;
    }
    __syncthreads();
    if (threadIdx.x == 0) *done = 0;   // re-arm for next conv / next replay
  }
}

// ======================= convs (gather + matmul + BN partials + stats tail) ==========
__global__ void k_conv64(const int* __restrict__ rp, const int* __restrict__ col,
                         const float* __restrict__ dinv, const float* __restrict__ x,
                         const float* __restrict__ W, float* __restrict__ out,
                         float* __restrict__ part, float* __restrict__ stats,
                         int* __restrict__ done, int n){
  __shared__ float yl[4][64];
  __shared__ float ls[64], lq[64];
  int lane = threadIdx.x & 63, w = threadIdx.x >> 6;
  if (threadIdx.x < 64){ ls[threadIdx.x] = 0.f; lq[threadIdx.x] = 0.f; }
  __syncthreads();
  float sa = 0.f, sq = 0.f;
  int wid = blockIdx.x*4 + w, nw = gridDim.x*4;
  for (int i = wid; i < n; i += nw){
    int beg = rp[i], end = rp[i+1];
    float di = dinv[i];
    float y = 0.f;
    int j = beg;
    for (; j + 4 <= end; j += 4){
      int s0 = col[j], s1 = col[j+1], s2 = col[j+2], s3 = col[j+3];
      float y0 = dinv[s0]*x[s0*64+lane];
      float y1 = dinv[s1]*x[s1*64+lane];
      float y2 = dinv[s2]*x[s2*64+lane];
      float y3 = dinv[s3]*x[s3*64+lane];
      y += (y0+y1) + (y2+y3);
    }
    for (; j < end; j++){ int s = col[j]; y += dinv[s]*x[s*64+lane]; }
    y = di*y + 2.f*di*di*x[i*64+lane];
    yl[w][lane] = y;
    float acc = 0.f;
    #pragma unroll
    for (int k2 = 0; k2 < 64; k2++)
      acc += yl[w][k2]*W[k2*64+lane];
    out[i*64+lane] = acc;
    sa += acc; sq += acc*acc;
  }
  atomicAdd(&ls[lane], sa); atomicAdd(&lq[lane], sq);
  __syncthreads();
  if (threadIdx.x < 128)
    part[blockIdx.x*128 + threadIdx.x] =
      (threadIdx.x < 64) ? ls[threadIdx.x] : lq[threadIdx.x-64];
  conv_stats_tail(part, stats, done);
}

__global__ void k_conv3(const int* __restrict__ rp, const int* __restrict__ col,
                        const float* __restrict__ dinv, const float* __restrict__ x,
                        const float* __restrict__ W, float* __restrict__ out,
                        float* __restrict__ part, float* __restrict__ stats,
                        int* __restrict__ done, int n){
  __shared__ float ls[64], lq[64];
  int lane = threadIdx.x & 63, w = threadIdx.x >> 6;
  if (threadIdx.x < 64){ ls[threadIdx.x] = 0.f; lq[threadIdx.x] = 0.f; }
  __syncthreads();
  float wf0 = W[lane], wf1 = W[64+lane], wf2 = W[128+lane];
  float sa = 0.f, sq = 0.f;
  int wid = blockIdx.x*4 + w, nw = gridDim.x*4;
  for (int i = wid; i < n; i += nw){
    int beg = rp[i], end = rp[i+1];
    float a0 = 0.f, a1 = 0.f, a2 = 0.f;
    for (int j = beg + lane; j < end; j += 64){
      int s2 = col[j];
      float ds = dinv[s2];
      a0 += ds*x[s2*3+0]; a1 += ds*x[s2*3+1]; a2 += ds*x[s2*3+2];
    }
    for (int o = 32; o > 0; o >>= 1){
      a0 += __shfl_xor(a0, o); a1 += __shfl_xor(a1, o); a2 += __shfl_xor(a2, o);
    }
    float di = dinv[i];
    float sl = 2.f*di*di;
    a0 = di*a0 + sl*x[i*3+0];
    a1 = di*a1 + sl*x[i*3+1];
    a2 = di*a2 + sl*x[i*3+2];
    float s = a0*wf0 + a1*wf1 + a2*wf2;
    out[i*64+lane] = s; sa += s; sq += s*s;
  }
  atomicAdd(&ls[lane], sa); atomicAdd(&lq[lane], sq);
  __syncthreads();
  if (threadIdx.x < 128)
    part[blockIdx.x*128 + threadIdx.x] =
      (threadIdx.x < 64) ? ls[threadIdx.x] : lq[threadIdx.x-64];
  conv_stats_tail(part, stats, done);
}

// ======================= pool: BN+ReLU (in-place) + score + key init =================
__global__ void k_bnrelu_score(float* __restrict__ x, const float* __restrict__ stats,
                               const float* __restrict__ gamma, const float* __restrict__ beta,
                               const float* __restrict__ pw,
                               float* __restrict__ score, unsigned* __restrict__ key,
                               int* __restrict__ idx, int n, int P){
  int lane = threadIdx.x & 63, w = threadIdx.x >> 6;
  int wid = blockIdx.x*4 + w, nw = gridDim.x*4;
  float inv_n = 1.f/(float)n;
  float mu = stats[lane]*inv_n;
  float var = stats[64+lane]*inv_n - mu*mu;
  float gs = gamma[lane]*(1.f/sqrtf(var+1e-5f));
  float bt = beta[lane];
  float pv = pw[lane];
  float q = pv*pv;
  for (int o = 32; o > 0; o >>= 1) q += __shfl_xor(q, o);
  float qn = 1.f/sqrtf(q);
  for (int i = wid; i < n; i += nw){
    float v = fmaxf(gs*(x[i*64+lane]-mu)+bt, 0.f);
    x[i*64+lane] = v;
    float s = v*pv;
    for (int o = 32; o > 0; o >>= 1) s += __shfl_xor(s, o);
    if (lane == 0){
      float sc = fmaxf(s*qn, 0.f);
      score[i] = sc; key[i] = ~__float_as_uint(sc); idx[i] = i;
    }
  }
  for (int g = n + wid; g < P; g += nw)
    if (lane == 0){ key[g] = 0xFFFFFFFFu; idx[g] = 0; }
}

// ======================= score radix sort (LDS hist, r0-exact) =======================
__global__ void k_radix_hist(const unsigned* __restrict__ key, int* __restrict__ hist,
                             int shift, int nblk){
  __shared__ int lh[256];
  lh[threadIdx.x] = 0; __syncthreads();
  int base = blockIdx.x*1024 + threadIdx.x;
  #pragma unroll
  for (int u = 0; u < 4; u++){
    unsigned d = (key[base + u*256] >> shift) & 255u;
    atomicAdd(&lh[d], 1);
  }
  __syncthreads();
  hist[threadIdx.x*nblk + blockIdx.x] = lh[threadIdx.x];
}

__global__ void k_radix_scatter(const unsigned* __restrict__ keyin, const int* __restrict__ idxin,
                                unsigned* __restrict__ keyout, int* __restrict__ idxout,
                                const int* __restrict__ hist, int shift, int nblk){
  __shared__ int dbase[256], run[256], sc[256];
  __shared__ int wcnt[4][256];
  int t = threadIdx.x, lane = t & 63, w = t >> 6;
  int pre = 0, tot = 0;
  for (int b = 0; b < nblk; b++){
    int v = hist[t*nblk + b];
    if (b < blockIdx.x) pre += v;
    tot += v;
  }
  sc[t] = tot; __syncthreads();
  for (int st = 1; st < 256; st <<= 1){
    int a = (t >= st) ? sc[t-st] : 0; __syncthreads();
    sc[t] += a; __syncthreads();
  }
  dbase[t] = sc[t] - tot + pre;
  run[t] = 0;
  for (int u = 0; u < 4; u++){
    wcnt[0][t] = 0; wcnt[1][t] = 0; wcnt[2][t] = 0; wcnt[3][t] = 0;
    __syncthreads();
    int g = blockIdx.x*1024 + u*256 + t;
    unsigned kk = keyin[g]; int id = idxin[g];
    unsigned d = (kk >> shift) & 255u;
    unsigned long long m = ~0ull;
    #pragma unroll
    for (int b = 0; b < 8; b++){
      unsigned long long bal = __ballot((d >> b) & 1u);
      m &= ((d >> b) & 1u) ? bal : ~bal;
    }
    int rnk = __popcll(m & ((1ull << lane) - 1ull));
    if (rnk == 0) wcnt[w][d] = __popcll(m);
    __syncthreads();
    int off2 = run[d] + rnk;
    for (int w2 = 0; w2 < w; w2++) off2 += wcnt[w2][d];
    int pos = dbase[d] + off2;
    keyout[pos] = kk; idxout[pos] = id;
    __syncthreads();
    run[t] += wcnt[0][t] + wcnt[1][t] + wcnt[2][t] + wcnt[3][t];
    __syncthreads();
  }
}

// ======================= select + gather-scale =======================
__global__ void k_select_gather(const int* __restrict__ idxs, const float* __restrict__ x,
                                const float* __restrict__ score, int* __restrict__ perm,
                                int* __restrict__ mapv, float* __restrict__ xk, int n, int k){
  int t = blockIdx.x*blockDim.x + threadIdx.x;
  if (t < n){
    int i = idxs[t];
    mapv[i] = (t < k) ? t : -1;
    if (t < k) perm[t] = i;
  }
  if (t < k*64){
    int r = t >> 6, f = t & 63;
    int i = idxs[r];
    xk[t] = x[i*64+f]*score[i];
  }
}

// ======================= child CSR from parent CSR + injective mapping ================
__global__ void k_hist_mapped(const int* __restrict__ rp_p, const int* __restrict__ col_p,
                              const int* __restrict__ mapv, int* __restrict__ indeg, int np){
  int d = blockIdx.x*blockDim.x + threadIdx.x;
  if (d >= np) return;
  int md = mapv[d];
  if (md < 0) return;
  int c = 0, e = rp_p[d+1];
  int j = rp_p[d];
  for (; j + 4 <= e; j += 4){
    int c0 = (mapv[col_p[j]]   >= 0);
    int c1 = (mapv[col_p[j+1]] >= 0);
    int c2 = (mapv[col_p[j+2]] >= 0);
    int c3 = (mapv[col_p[j+3]] >= 0);
    c += (c0+c1) + (c2+c3);
  }
  for (; j < e; j++) if (mapv[col_p[j]] >= 0) c++;
  indeg[md] = c;
}

__global__ void k_scatter_mapped(const int* __restrict__ rp_p, const int* __restrict__ col_p,
                                 const int* __restrict__ mapv, const int* __restrict__ rp_c,
                                 int* __restrict__ col_c, int np){
  int d = blockIdx.x*blockDim.x + threadIdx.x;
  if (d >= np) return;
  int md = mapv[d];
  if (md < 0) return;
  int pos = rp_c[md], e = rp_p[d+1];
  int j = rp_p[d];
  for (; j + 4 <= e; j += 4){
    int m0 = mapv[col_p[j]], m1 = mapv[col_p[j+1]];
    int m2 = mapv[col_p[j+2]], m3 = mapv[col_p[j+3]];
    if (m0 >= 0) col_c[pos++] = m0;
    if (m1 >= 0) col_c[pos++] = m1;
    if (m2 >= 0) col_c[pos++] = m2;
    if (m3 >= 0) col_c[pos++] = m3;
  }
  for (; j < e; j++){
    int ms = mapv[col_p[j]];
    if (ms >= 0) col_c[pos++] = ms;
  }
}

// ======================= up-path BN+ReLU + scatter-add =======================
__global__ void k_bnrelu_scatter(const float* __restrict__ x, const float* __restrict__ stats,
                                 const float* __restrict__ gamma, const float* __restrict__ beta,
                                 const int* __restrict__ perm, float* __restrict__ res, int n){
  int t = blockIdx.x*blockDim.x + threadIdx.x;
  if (t >= n*64) return;
  int r = t >> 6, f = t & 63;
  float inv_n = 1.0f/(float)n;
  float mu = stats[f]*inv_n;
  float var = stats[64+f]*inv_n - mu*mu;
  float v = gamma[f]*(x[t]-mu)*(1.0f/sqrtf(var+1e-5f)) + beta[f];
  res[perm[r]*64+f] += fmaxf(v, 0.f);
}

// ======================= final conv =======================
__global__ void k_matvec(const float* __restrict__ x, const float* __restrict__ W,
                         float* __restrict__ h1, int n){
  int lane = threadIdx.x & 63, w = threadIdx.x >> 6;
  int wid = blockIdx.x*4 + w, nw = gridDim.x*4;
  float wv = W[lane];
  for (int i = wid; i < n; i += nw){
    float v = x[i*64+lane]*wv;
    for (int o = 32; o > 0; o >>= 1) v += __shfl_xor(v, o);
    if (lane == 0) h1[i] = v;
  }
}

__global__ void k_gather_sig(const int* __restrict__ rp, const int* __restrict__ col,
                             const float* __restrict__ dinv, const float* __restrict__ h1,
                             float* __restrict__ out, int n){
  int i = blockIdx.x*blockDim.x + threadIdx.x;
  if (i >= n) return;
  int beg = rp[i], end = rp[i+1];
  float di = dinv[i];
  float acc = 0.f;
  int j = beg;
  for (; j + 4 <= end; j += 4){
    int s0 = col[j], s1 = col[j+1], s2 = col[j+2], s3 = col[j+3];
    float v0 = dinv[s0]*h1[s0];
    float v1 = dinv[s1]*h1[s1];
    float v2 = dinv[s2]*h1[s2];
    float v3 = dinv[s3]*h1[s3];
    acc += (v0+v1) + (v2+v3);
  }
  for (; j < end; j++) acc += dinv[col[j]]*h1[col[j]];
  float v = di*acc + di*di*h1[i];
  out[i] = 1.f/(1.f+expf(-v));
}

// ======================= host =======================

extern "C" void kernel_launch(void* const* d_in, const int* in_sizes, int n_in,
                              void* d_out, int out_size, void* d_ws, size_t ws_size,
                              hipStream_t stream) {
  const float* x_in = (const float*)d_in[0];
  const int* ei = (const int*)d_in[1];
  const int* src0 = ei;
  const int* dst0 = ei + NE;
  const float* W_d[4] = {(const float*)d_in[2],(const float*)d_in[5],(const float*)d_in[8],(const float*)d_in[11]};
  const float* g_d[4] = {(const float*)d_in[3],(const float*)d_in[6],(const float*)d_in[9],(const float*)d_in[12]};
  const float* b_d[4] = {(const float*)d_in[4],(const float*)d_in[7],(const float*)d_in[10],(const float*)d_in[13]};
  const float* pw[3]  = {(const float*)d_in[14],(const float*)d_in[15],(const float*)d_in[16]};
  const float* W_u[2] = {(const float*)d_in[17],(const float*)d_in[20]};
  const float* g_u[2] = {(const float*)d_in[18],(const float*)d_in[21]};
  const float* b_u[2] = {(const float*)d_in[19],(const float*)d_in[22]};
  const float* W_out  = (const float*)d_in[23];
  float* out = (float*)d_out;

  float* base = (float*)d_ws;
  size_t off = 0;
  auto alloc = [&](size_t nf){ float* p = base + off; off += nf; return p; };
  float* x0 = alloc(5120000);
  float* x1 = alloc(2560000);
  float* x2 = alloc(1280000);
  float* x3 = alloc(640000);
  float* A  = alloc(2560000);
  int* col0 = (int*)alloc(NE);
  int* col1 = (int*)alloc(NE);
  int* col2 = (int*)alloc(NE);
  int* col3 = (int*)alloc(NE);
  int* rp0 = (int*)alloc(80001);
  int* rp1 = (int*)alloc(40001);
  int* rp2 = (int*)alloc(20001);
  int* rp3 = (int*)alloc(10001);
  int* cur0 = (int*)alloc(NN0);
  int* indeg  = (int*)alloc(NN0);
  int* done = (int*)alloc(1);          // contiguous after indeg -> one memset
  float* dinv0  = alloc(NN0);
  float* dinv0f = alloc(NN0);
  float* dinv1  = alloc(40000);
  float* dinv2  = alloc(20000);
  float* dinv3  = alloc(10000);
  float* score = alloc(NN0);
  int* mapv = (int*)alloc(NN0);
  int* p0 = (int*)alloc(40000);
  int* p1 = (int*)alloc(20000);
  int* p2 = (int*)alloc(10000);
  float* stats = alloc(128);
  float* part  = alloc(MMB_GRID*128);
  unsigned* keyA = (unsigned*)alloc(81920);
  unsigned* keyB = (unsigned*)alloc(81920);
  int* idxA = (int*)alloc(81920);
  int* idxB = (int*)alloc(81920);
  int* hist = (int*)alloc(81920);
  (void)ws_size; (void)in_sizes; (void)n_in; (void)out_size;

  const int B = 256;

  // ---- level-0 CSR (atomic build; random-target atomics only) ----
  hipMemsetAsync(indeg, 0, (NN0 + 1)*sizeof(int), stream);   // indeg + done
  k_deg0<<<1024, B, 0, stream>>>(dst0, indeg);
  k_scan_rp<<<cdiv(NN0,2048), B, 0, stream>>>(indeg, rp0, cur0, dinv0, dinv0f, NN0);
  k_escat0<<<1024, B, 0, stream>>>(dst0, src0, cur0, col0);

  auto pool = [&](float* xb, const float* gm, const float* bt, const float* pwv,
                  int n, int k, int* pm){
    int nblk = cdiv(n, 1024), P = nblk*1024;
    k_bnrelu_score<<<1024, B, 0, stream>>>(xb, stats, gm, bt, pwv, score, keyA, idxA, n, P);
    unsigned* ka = keyA; int* ia = idxA; unsigned* kb = keyB; int* ib = idxB;
    for (int pass = 0; pass < 4; pass++){
      k_radix_hist   <<<nblk, B, 0, stream>>>(ka, hist, pass*8, nblk);
      k_radix_scatter<<<nblk, B, 0, stream>>>(ka, ia, kb, ib, hist, pass*8, nblk);
      unsigned* tk = ka; ka = kb; kb = tk;
      int* ti = ia; ia = ib; ib = ti;
    }
    k_select_gather<<<cdiv(k*64,B), B, 0, stream>>>(ia, xb, score, pm, mapv, A, n, k);
  };

  auto csr_mapped = [&](const int* rp_p, const int* col_p, int np, int nc,
                        int* rp_c, int* col_c, float* dv){
    k_hist_mapped<<<cdiv(np,B), B, 0, stream>>>(rp_p, col_p, mapv, indeg, np);
    k_scan_rp<<<cdiv(nc,2048), B, 0, stream>>>(indeg, rp_c, nullptr, dv, nullptr, nc);
    k_scatter_mapped<<<cdiv(np,B), B, 0, stream>>>(rp_p, col_p, mapv, rp_c, col_c, np);
  };

  // ---- down path ----
  k_conv3<<<MMB_GRID, B, 0, stream>>>(rp0, col0, dinv0, x_in, W_d[0], x0, part, stats, done, NN0);
  pool(x0, g_d[0], b_d[0], pw[0], NN0, 40000, p0);
  csr_mapped(rp0, col0, NN0, 40000, rp1, col1, dinv1);

  k_conv64<<<MMB_GRID, B, 0, stream>>>(rp1, col1, dinv1, A, W_d[1], x1, part, stats, done, 40000);
  pool(x1, g_d[1], b_d[1], pw[1], 40000, 20000, p1);
  csr_mapped(rp1, col1, 40000, 20000, rp2, col2, dinv2);

  k_conv64<<<MMB_GRID, B, 0, stream>>>(rp2, col2, dinv2, A, W_d[2], x2, part, stats, done, 20000);
  pool(x2, g_d[2], b_d[2], pw[2], 20000, 10000, p2);
  csr_mapped(rp2, col2, 20000, 10000, rp3, col3, dinv3);

  k_conv64<<<MMB_GRID, B, 0, stream>>>(rp3, col3, dinv3, A, W_d[3], x3, part, stats, done, 10000);

  // ---- up path (BN+ReLU fused into the skip-connection scatter-add) ----
  k_bnrelu_scatter<<<cdiv(10000*64,B), B, 0, stream>>>(x3, stats, g_d[3], b_d[3], p2, x2, 10000);
  k_conv64<<<MMB_GRID, B, 0, stream>>>(rp2, col2, dinv2, x2, W_u[0], A, part, stats, done, 20000);
  k_bnrelu_scatter<<<cdiv(20000*64,B), B, 0, stream>>>(A, stats, g_u[0], b_u[0], p1, x1, 20000);
  k_conv64<<<MMB_GRID, B, 0, stream>>>(rp1, col1, dinv1, x1, W_u[1], A, part, stats, done, 40000);
  k_bnrelu_scatter<<<cdiv(40000*64,B), B, 0, stream>>>(A, stats, g_u[1], b_u[1], p0, x0, 40000);

  // ---- final conv (fill = 1.0) fused with sigmoid ----
  float* h1 = score;  // reuse
  k_matvec<<<512, B, 0, stream>>>(x0, W_out, h1, NN0);
  k_gather_sig<<<cdiv(NN0,B), B, 0, stream>>>(rp0, col0, dinv0f, h1, out, NN0);
}

// Round 5
// 886.797 us; speedup vs baseline: 7.3640x; 2.3023x over previous
//
#include <hip/hip_runtime.h>
#include <cstdint>

#define NN0 80000
#define NE 1280000
#define MMB_GRID 2048

static inline int cdiv(int a, int b){ return (a+b-1)/b; }

// ======================= level-0 CSR build (atomic, random-target) =======================
__global__ void k_deg0(const int* __restrict__ dst, int* __restrict__ indeg){
  for (int e = blockIdx.x*blockDim.x + threadIdx.x; e < NE; e += gridDim.x*blockDim.x)
    atomicAdd(&indeg[dst[e]], 1);
}

__global__ void k_escat0(const int* __restrict__ dst, const int* __restrict__ srcv,
                         int* __restrict__ cur, int* __restrict__ col){
  for (int e = blockIdx.x*blockDim.x + threadIdx.x; e < NE; e += gridDim.x*blockDim.x){
    int d = dst[e];
    int pos = atomicAdd(&cur[d], 1);
    col[pos] = srcv[e];
  }
}

// ======================= fused single-dispatch scan =======================
// Each block redundantly sums in[0 .. blockIdx*2048) (L2-resident, nb <= 40).
__global__ void k_scan_rp(const int* __restrict__ in, int* __restrict__ rp,
                          int* __restrict__ cur, float* __restrict__ dA,
                          float* __restrict__ dB, int n){
  __shared__ int ws[256];
  int t = threadIdx.x;
  int pre = blockIdx.x*2048;
  int s = 0;
  for (int i = t; i < pre; i += 256) s += in[i];
  ws[t] = s; __syncthreads();
  for (int st = 128; st > 0; st >>= 1){
    if (t < st) ws[t] += ws[t+st];
    __syncthreads();
  }
  int blockoff = ws[0];
  __syncthreads();
  int base = pre + t*8;
  int v[8]; int ls = 0;
  #pragma unroll
  for (int u = 0; u < 8; u++){ int i = base+u; v[u] = (i < n) ? in[i] : 0; ls += v[u]; }
  ws[t] = ls; __syncthreads();
  for (int st = 1; st < 256; st <<= 1){
    int a = (t >= st) ? ws[t-st] : 0; __syncthreads();
    ws[t] += a; __syncthreads();
  }
  int off = blockoff + ws[t] - ls;
  #pragma unroll
  for (int u = 0; u < 8; u++){
    int i = base+u;
    if (i < n){
      rp[i] = off;
      if (cur) cur[i] = off;
      off += v[u];
      dA[i] = 1.0f/sqrtf((float)v[u] + 2.f);
      if (dB) dB[i] = 1.0f/sqrtf((float)v[u] + 1.f);
      if (i == n-1) rp[n] = off;
    }
  }
}

// ======================= convs (gather + matmul + BN partials) =======================
// NOTE: no same-address atomics here — stats are reduced by k_stats_reduce.
// (round-4 lesson: same-address device atomics serialize at ~10M/s; a 2048-block
// "last-block" election cost +210us per conv.)
__global__ void k_conv64(const int* __restrict__ rp, const int* __restrict__ col,
                         const float* __restrict__ dinv, const float* __restrict__ x,
                         const float* __restrict__ W, float* __restrict__ out,
                         float* __restrict__ part, int n){
  __shared__ float yl[4][64];
  __shared__ float ls[64], lq[64];
  int lane = threadIdx.x & 63, w = threadIdx.x >> 6;
  if (threadIdx.x < 64){ ls[threadIdx.x] = 0.f; lq[threadIdx.x] = 0.f; }
  __syncthreads();
  float sa = 0.f, sq = 0.f;
  int wid = blockIdx.x*4 + w, nw = gridDim.x*4;
  for (int i = wid; i < n; i += nw){
    int beg = rp[i], end = rp[i+1];
    float di = dinv[i];
    float y = 0.f;
    int j = beg;
    for (; j + 4 <= end; j += 4){
      int s0 = col[j], s1 = col[j+1], s2 = col[j+2], s3 = col[j+3];
      float y0 = dinv[s0]*x[s0*64+lane];
      float y1 = dinv[s1]*x[s1*64+lane];
      float y2 = dinv[s2]*x[s2*64+lane];
      float y3 = dinv[s3]*x[s3*64+lane];
      y += (y0+y1) + (y2+y3);
    }
    for (; j < end; j++){ int s = col[j]; y += dinv[s]*x[s*64+lane]; }
    y = di*y + 2.f*di*di*x[i*64+lane];
    yl[w][lane] = y;
    float acc = 0.f;
    #pragma unroll
    for (int k2 = 0; k2 < 64; k2++)
      acc += yl[w][k2]*W[k2*64+lane];
    out[i*64+lane] = acc;
    sa += acc; sq += acc*acc;
  }
  atomicAdd(&ls[lane], sa); atomicAdd(&lq[lane], sq);
  __syncthreads();
  if (threadIdx.x < 128)
    part[blockIdx.x*128 + threadIdx.x] =
      (threadIdx.x < 64) ? ls[threadIdx.x] : lq[threadIdx.x-64];
}

__global__ void k_conv3(const int* __restrict__ rp, const int* __restrict__ col,
                        const float* __restrict__ dinv, const float* __restrict__ x,
                        const float* __restrict__ W, float* __restrict__ out,
                        float* __restrict__ part, int n){
  __shared__ float ls[64], lq[64];
  int lane = threadIdx.x & 63, w = threadIdx.x >> 6;
  if (threadIdx.x < 64){ ls[threadIdx.x] = 0.f; lq[threadIdx.x] = 0.f; }
  __syncthreads();
  float wf0 = W[lane], wf1 = W[64+lane], wf2 = W[128+lane];
  float sa = 0.f, sq = 0.f;
  int wid = blockIdx.x*4 + w, nw = gridDim.x*4;
  for (int i = wid; i < n; i += nw){
    int beg = rp[i], end = rp[i+1];
    float a0 = 0.f, a1 = 0.f, a2 = 0.f;
    for (int j = beg + lane; j < end; j += 64){
      int s2 = col[j];
      float ds = dinv[s2];
      a0 += ds*x[s2*3+0]; a1 += ds*x[s2*3+1]; a2 += ds*x[s2*3+2];
    }
    for (int o = 32; o > 0; o >>= 1){
      a0 += __shfl_xor(a0, o); a1 += __shfl_xor(a1, o); a2 += __shfl_xor(a2, o);
    }
    float di = dinv[i];
    float sl = 2.f*di*di;
    a0 = di*a0 + sl*x[i*3+0];
    a1 = di*a1 + sl*x[i*3+1];
    a2 = di*a2 + sl*x[i*3+2];
    float s = a0*wf0 + a1*wf1 + a2*wf2;
    out[i*64+lane] = s; sa += s; sq += s*s;
  }
  atomicAdd(&ls[lane], sa); atomicAdd(&lq[lane], sq);
  __syncthreads();
  if (threadIdx.x < 128)
    part[blockIdx.x*128 + threadIdx.x] =
      (threadIdx.x < 64) ? ls[threadIdx.x] : lq[threadIdx.x-64];
}

__global__ void k_stats_reduce(const float* __restrict__ part, float* __restrict__ stats){
  int c = blockIdx.x, lane = threadIdx.x;
  float s = 0.f;
  for (int b = lane; b < MMB_GRID; b += 64) s += part[b*128 + c];
  for (int o = 32; o > 0; o >>= 1) s += __shfl_xor(s, o);
  if (lane == 0) stats[c] = s;
}

// ======================= pool: BN+ReLU (in-place) + score + key init =================
__global__ void k_bnrelu_score(float* __restrict__ x, const float* __restrict__ stats,
                               const float* __restrict__ gamma, const float* __restrict__ beta,
                               const float* __restrict__ pw,
                               float* __restrict__ score, unsigned* __restrict__ key,
                               int* __restrict__ idx, int n, int P){
  int lane = threadIdx.x & 63, w = threadIdx.x >> 6;
  int wid = blockIdx.x*4 + w, nw = gridDim.x*4;
  float inv_n = 1.f/(float)n;
  float mu = stats[lane]*inv_n;
  float var = stats[64+lane]*inv_n - mu*mu;
  float gs = gamma[lane]*(1.f/sqrtf(var+1e-5f));
  float bt = beta[lane];
  float pv = pw[lane];
  float q = pv*pv;
  for (int o = 32; o > 0; o >>= 1) q += __shfl_xor(q, o);
  float qn = 1.f/sqrtf(q);
  for (int i = wid; i < n; i += nw){
    float v = fmaxf(gs*(x[i*64+lane]-mu)+bt, 0.f);
    x[i*64+lane] = v;
    float s = v*pv;
    for (int o = 32; o > 0; o >>= 1) s += __shfl_xor(s, o);
    if (lane == 0){
      float sc = fmaxf(s*qn, 0.f);
      score[i] = sc; key[i] = ~__float_as_uint(sc); idx[i] = i;
    }
  }
  for (int g = n + wid; g < P; g += nw)
    if (lane == 0){ key[g] = 0xFFFFFFFFu; idx[g] = 0; }
}

// ======================= score radix sort (LDS hist, stable, exact) =======================
__global__ void k_radix_hist(const unsigned* __restrict__ key, int* __restrict__ hist,
                             int shift, int nblk){
  __shared__ int lh[256];
  lh[threadIdx.x] = 0; __syncthreads();
  int base = blockIdx.x*1024 + threadIdx.x;
  #pragma unroll
  for (int u = 0; u < 4; u++){
    unsigned d = (key[base + u*256] >> shift) & 255u;
    atomicAdd(&lh[d], 1);
  }
  __syncthreads();
  hist[threadIdx.x*nblk + blockIdx.x] = lh[threadIdx.x];
}

__global__ void k_radix_scatter(const unsigned* __restrict__ keyin, const int* __restrict__ idxin,
                                unsigned* __restrict__ keyout, int* __restrict__ idxout,
                                const int* __restrict__ hist, int shift, int nblk){
  __shared__ int dbase[256], run[256], sc[256];
  __shared__ int wcnt[4][256];
  int t = threadIdx.x, lane = t & 63, w = t >> 6;
  int pre = 0, tot = 0;
  for (int b = 0; b < nblk; b++){
    int v = hist[t*nblk + b];
    if (b < blockIdx.x) pre += v;
    tot += v;
  }
  sc[t] = tot; __syncthreads();
  for (int st = 1; st < 256; st <<= 1){
    int a = (t >= st) ? sc[t-st] : 0; __syncthreads();
    sc[t] += a; __syncthreads();
  }
  dbase[t] = sc[t] - tot + pre;
  run[t] = 0;
  for (int u = 0; u < 4; u++){
    wcnt[0][t] = 0; wcnt[1][t] = 0; wcnt[2][t] = 0; wcnt[3][t] = 0;
    __syncthreads();
    int g = blockIdx.x*1024 + u*256 + t;
    unsigned kk = keyin[g]; int id = idxin[g];
    unsigned d = (kk >> shift) & 255u;
    unsigned long long m = ~0ull;
    #pragma unroll
    for (int b = 0; b < 8; b++){
      unsigned long long bal = __ballot((d >> b) & 1u);
      m &= ((d >> b) & 1u) ? bal : ~bal;
    }
    int rnk = __popcll(m & ((1ull << lane) - 1ull));
    if (rnk == 0) wcnt[w][d] = __popcll(m);
    __syncthreads();
    int off2 = run[d] + rnk;
    for (int w2 = 0; w2 < w; w2++) off2 += wcnt[w2][d];
    int pos = dbase[d] + off2;
    keyout[pos] = kk; idxout[pos] = id;
    __syncthreads();
    run[t] += wcnt[0][t] + wcnt[1][t] + wcnt[2][t] + wcnt[3][t];
    __syncthreads();
  }
}

// ======================= select + gather-scale =======================
__global__ void k_select_gather(const int* __restrict__ idxs, const float* __restrict__ x,
                                const float* __restrict__ score, int* __restrict__ perm,
                                int* __restrict__ mapv, float* __restrict__ xk, int n, int k){
  int t = blockIdx.x*blockDim.x + threadIdx.x;
  if (t < n){
    int i = idxs[t];
    mapv[i] = (t < k) ? t : -1;
    if (t < k) perm[t] = i;
  }
  if (t < k*64){
    int r = t >> 6, f = t & 63;
    int i = idxs[r];
    xk[t] = x[i*64+f]*score[i];
  }
}

// ======================= child CSR from parent CSR + injective mapping ================
__global__ void k_hist_mapped(const int* __restrict__ rp_p, const int* __restrict__ col_p,
                              const int* __restrict__ mapv, int* __restrict__ indeg, int np){
  int d = blockIdx.x*blockDim.x + threadIdx.x;
  if (d >= np) return;
  int md = mapv[d];
  if (md < 0) return;
  int c = 0, e = rp_p[d+1];
  int j = rp_p[d];
  for (; j + 4 <= e; j += 4){
    int c0 = (mapv[col_p[j]]   >= 0);
    int c1 = (mapv[col_p[j+1]] >= 0);
    int c2 = (mapv[col_p[j+2]] >= 0);
    int c3 = (mapv[col_p[j+3]] >= 0);
    c += (c0+c1) + (c2+c3);
  }
  for (; j < e; j++) if (mapv[col_p[j]] >= 0) c++;
  indeg[md] = c;
}

__global__ void k_scatter_mapped(const int* __restrict__ rp_p, const int* __restrict__ col_p,
                                 const int* __restrict__ mapv, const int* __restrict__ rp_c,
                                 int* __restrict__ col_c, int np){
  int d = blockIdx.x*blockDim.x + threadIdx.x;
  if (d >= np) return;
  int md = mapv[d];
  if (md < 0) return;
  int pos = rp_c[md], e = rp_p[d+1];
  int j = rp_p[d];
  for (; j + 4 <= e; j += 4){
    int m0 = mapv[col_p[j]], m1 = mapv[col_p[j+1]];
    int m2 = mapv[col_p[j+2]], m3 = mapv[col_p[j+3]];
    if (m0 >= 0) col_c[pos++] = m0;
    if (m1 >= 0) col_c[pos++] = m1;
    if (m2 >= 0) col_c[pos++] = m2;
    if (m3 >= 0) col_c[pos++] = m3;
  }
  for (; j < e; j++){
    int ms = mapv[col_p[j]];
    if (ms >= 0) col_c[pos++] = ms;
  }
}

// ======================= up-path BN+ReLU + scatter-add =======================
__global__ void k_bnrelu_scatter(const float* __restrict__ x, const float* __restrict__ stats,
                                 const float* __restrict__ gamma, const float* __restrict__ beta,
                                 const int* __restrict__ perm, float* __restrict__ res, int n){
  int t = blockIdx.x*blockDim.x + threadIdx.x;
  if (t >= n*64) return;
  int r = t >> 6, f = t & 63;
  float inv_n = 1.0f/(float)n;
  float mu = stats[f]*inv_n;
  float var = stats[64+f]*inv_n - mu*mu;
  float v = gamma[f]*(x[t]-mu)*(1.0f/sqrtf(var+1e-5f)) + beta[f];
  res[perm[r]*64+f] += fmaxf(v, 0.f);
}

// ======================= final conv =======================
__global__ void k_matvec(const float* __restrict__ x, const float* __restrict__ W,
                         float* __restrict__ h1, int n){
  int lane = threadIdx.x & 63, w = threadIdx.x >> 6;
  int wid = blockIdx.x*4 + w, nw = gridDim.x*4;
  float wv = W[lane];
  for (int i = wid; i < n; i += nw){
    float v = x[i*64+lane]*wv;
    for (int o = 32; o > 0; o >>= 1) v += __shfl_xor(v, o);
    if (lane == 0) h1[i] = v;
  }
}

__global__ void k_gather_sig(const int* __restrict__ rp, const int* __restrict__ col,
                             const float* __restrict__ dinv, const float* __restrict__ h1,
                             float* __restrict__ out, int n){
  int i = blockIdx.x*blockDim.x + threadIdx.x;
  if (i >= n) return;
  int beg = rp[i], end = rp[i+1];
  float di = dinv[i];
  float acc = 0.f;
  int j = beg;
  for (; j + 4 <= end; j += 4){
    int s0 = col[j], s1 = col[j+1], s2 = col[j+2], s3 = col[j+3];
    float v0 = dinv[s0]*h1[s0];
    float v1 = dinv[s1]*h1[s1];
    float v2 = dinv[s2]*h1[s2];
    float v3 = dinv[s3]*h1[s3];
    acc += (v0+v1) + (v2+v3);
  }
  for (; j < end; j++) acc += dinv[col[j]]*h1[col[j]];
  float v = di*acc + di*di*h1[i];
  out[i] = 1.f/(1.f+expf(-v));
}

// ======================= host =======================

extern "C" void kernel_launch(void* const* d_in, const int* in_sizes, int n_in,
                              void* d_out, int out_size, void* d_ws, size_t ws_size,
                              hipStream_t stream) {
  const float* x_in = (const float*)d_in[0];
  const int* ei = (const int*)d_in[1];
  const int* src0 = ei;
  const int* dst0 = ei + NE;
  const float* W_d[4] = {(const float*)d_in[2],(const float*)d_in[5],(const float*)d_in[8],(const float*)d_in[11]};
  const float* g_d[4] = {(const float*)d_in[3],(const float*)d_in[6],(const float*)d_in[9],(const float*)d_in[12]};
  const float* b_d[4] = {(const float*)d_in[4],(const float*)d_in[7],(const float*)d_in[10],(const float*)d_in[13]};
  const float* pw[3]  = {(const float*)d_in[14],(const float*)d_in[15],(const float*)d_in[16]};
  const float* W_u[2] = {(const float*)d_in[17],(const float*)d_in[20]};
  const float* g_u[2] = {(const float*)d_in[18],(const float*)d_in[21]};
  const float* b_u[2] = {(const float*)d_in[19],(const float*)d_in[22]};
  const float* W_out  = (const float*)d_in[23];
  float* out = (float*)d_out;

  float* base = (float*)d_ws;
  size_t off = 0;
  auto alloc = [&](size_t nf){ float* p = base + off; off += nf; return p; };
  float* x0 = alloc(5120000);
  float* x1 = alloc(2560000);
  float* x2 = alloc(1280000);
  float* x3 = alloc(640000);
  float* A  = alloc(2560000);
  int* col0 = (int*)alloc(NE);
  int* col1 = (int*)alloc(NE);
  int* col2 = (int*)alloc(NE);
  int* col3 = (int*)alloc(NE);
  int* rp0 = (int*)alloc(80001);
  int* rp1 = (int*)alloc(40001);
  int* rp2 = (int*)alloc(20001);
  int* rp3 = (int*)alloc(10001);
  int* cur0 = (int*)alloc(NN0);
  int* indeg  = (int*)alloc(NN0);
  float* dinv0  = alloc(NN0);
  float* dinv0f = alloc(NN0);
  float* dinv1  = alloc(40000);
  float* dinv2  = alloc(20000);
  float* dinv3  = alloc(10000);
  float* score = alloc(NN0);
  int* mapv = (int*)alloc(NN0);
  int* p0 = (int*)alloc(40000);
  int* p1 = (int*)alloc(20000);
  int* p2 = (int*)alloc(10000);
  float* stats = alloc(128);
  float* part  = alloc(MMB_GRID*128);
  unsigned* keyA = (unsigned*)alloc(81920);
  unsigned* keyB = (unsigned*)alloc(81920);
  int* idxA = (int*)alloc(81920);
  int* idxB = (int*)alloc(81920);
  int* hist = (int*)alloc(81920);
  (void)ws_size; (void)in_sizes; (void)n_in; (void)out_size;

  const int B = 256;

  // ---- level-0 CSR (atomic build; random-target atomics only) ----
  hipMemsetAsync(indeg, 0, NN0*sizeof(int), stream);
  k_deg0<<<1024, B, 0, stream>>>(dst0, indeg);
  k_scan_rp<<<cdiv(NN0,2048), B, 0, stream>>>(indeg, rp0, cur0, dinv0, dinv0f, NN0);
  k_escat0<<<1024, B, 0, stream>>>(dst0, src0, cur0, col0);

  auto conv = [&](const float* xin, const float* W, int n,
                  const int* rp, const int* col, const float* dv, float* dstb){
    k_conv64<<<MMB_GRID, B, 0, stream>>>(rp, col, dv, xin, W, dstb, part, n);
    k_stats_reduce<<<128, 64, 0, stream>>>(part, stats);
  };

  auto pool = [&](float* xb, const float* gm, const float* bt, const float* pwv,
                  int n, int k, int* pm){
    int nblk = cdiv(n, 1024), P = nblk*1024;
    k_bnrelu_score<<<1024, B, 0, stream>>>(xb, stats, gm, bt, pwv, score, keyA, idxA, n, P);
    unsigned* ka = keyA; int* ia = idxA; unsigned* kb = keyB; int* ib = idxB;
    for (int pass = 0; pass < 4; pass++){
      k_radix_hist   <<<nblk, B, 0, stream>>>(ka, hist, pass*8, nblk);
      k_radix_scatter<<<nblk, B, 0, stream>>>(ka, ia, kb, ib, hist, pass*8, nblk);
      unsigned* tk = ka; ka = kb; kb = tk;
      int* ti = ia; ia = ib; ib = ti;
    }
    k_select_gather<<<cdiv(k*64,B), B, 0, stream>>>(ia, xb, score, pm, mapv, A, n, k);
  };

  auto csr_mapped = [&](const int* rp_p, const int* col_p, int np, int nc,
                        int* rp_c, int* col_c, float* dv){
    k_hist_mapped<<<cdiv(np,B), B, 0, stream>>>(rp_p, col_p, mapv, indeg, np);
    k_scan_rp<<<cdiv(nc,2048), B, 0, stream>>>(indeg, rp_c, nullptr, dv, nullptr, nc);
    k_scatter_mapped<<<cdiv(np,B), B, 0, stream>>>(rp_p, col_p, mapv, rp_c, col_c, np);
  };

  // ---- down path ----
  k_conv3<<<MMB_GRID, B, 0, stream>>>(rp0, col0, dinv0, x_in, W_d[0], x0, part, NN0);
  k_stats_reduce<<<128, 64, 0, stream>>>(part, stats);
  pool(x0, g_d[0], b_d[0], pw[0], NN0, 40000, p0);
  csr_mapped(rp0, col0, NN0, 40000, rp1, col1, dinv1);

  conv(A, W_d[1], 40000, rp1, col1, dinv1, x1);
  pool(x1, g_d[1], b_d[1], pw[1], 40000, 20000, p1);
  csr_mapped(rp1, col1, 40000, 20000, rp2, col2, dinv2);

  conv(A, W_d[2], 20000, rp2, col2, dinv2, x2);
  pool(x2, g_d[2], b_d[2], pw[2], 20000, 10000, p2);
  csr_mapped(rp2, col2, 20000, 10000, rp3, col3, dinv3);

  conv(A, W_d[3], 10000, rp3, col3, dinv3, x3);

  // ---- up path (BN+ReLU fused into the skip-connection scatter-add) ----
  k_bnrelu_scatter<<<cdiv(10000*64,B), B, 0, stream>>>(x3, stats, g_d[3], b_d[3], p2, x2, 10000);
  conv(x2, W_u[0], 20000, rp2, col2, dinv2, A);
  k_bnrelu_scatter<<<cdiv(20000*64,B), B, 0, stream>>>(A, stats, g_u[0], b_u[0], p1, x1, 20000);
  conv(x1, W_u[1], 40000, rp1, col1, dinv1, A);
  k_bnrelu_scatter<<<cdiv(40000*64,B), B, 0, stream>>>(A, stats, g_u[1], b_u[1], p0, x0, 40000);

  // ---- final conv (fill = 1.0) fused with sigmoid ----
  float* h1 = score;  // reuse
  k_matvec<<<512, B, 0, stream>>>(x0, W_out, h1, NN0);
  k_gather_sig<<<cdiv(NN0,B), B, 0, stream>>>(rp0, col0, dinv0f, h1, out, NN0);
}

// Round 6
// 743.203 us; speedup vs baseline: 8.7868x; 1.1932x over previous
//
#include <hip/hip_runtime.h>
#include <cstdint>

#define NN0 80000
#define NE 1280000
#define MMB_GRID 2048
#define EB 2048          // elems per block in edge bucket pass (NE/EB = 625 exact)
#define ENB 625

static inline int cdiv(int a, int b){ return (a+b-1)/b; }

// ======================= edge bucket pass (r0 machinery, shift=11) =======================
__global__ void k_ehist6(const int* __restrict__ key, int* __restrict__ hist, int shift){
  __shared__ int lh[64];
  if (threadIdx.x < 64) lh[threadIdx.x] = 0;
  __syncthreads();
  int base = blockIdx.x*EB + threadIdx.x;
  #pragma unroll
  for (int u = 0; u < 8; u++)
    atomicAdd(&lh[(key[base + u*256] >> shift) & 63], 1);
  __syncthreads();
  if (threadIdx.x < 64) hist[threadIdx.x*ENB + blockIdx.x] = lh[threadIdx.x];
}

__global__ void k_scan_part(const int* __restrict__ in, int* __restrict__ bsum, int n){
  __shared__ int ws[256];
  int base = blockIdx.x*2048 + threadIdx.x*8;
  int s = 0;
  #pragma unroll
  for (int u = 0; u < 8; u++){ int i = base+u; if (i < n) s += in[i]; }
  ws[threadIdx.x] = s; __syncthreads();
  for (int st = 128; st > 0; st >>= 1){
    if (threadIdx.x < st) ws[threadIdx.x] += ws[threadIdx.x+st];
    __syncthreads();
  }
  if (threadIdx.x == 0) bsum[blockIdx.x] = ws[0];
}

__global__ void k_scan_fin_flat(int* __restrict__ data, const int* __restrict__ bsum, int nb, int n){
  __shared__ int bws[256]; __shared__ int ws[256];
  int t = threadIdx.x;
  bws[t] = (t < nb) ? bsum[t] : 0; __syncthreads();
  for (int st = 1; st < 256; st <<= 1){
    int a = (t >= st) ? bws[t-st] : 0; __syncthreads();
    bws[t] += a; __syncthreads();
  }
  int blockoff = (blockIdx.x == 0) ? 0 : bws[blockIdx.x-1];
  int base = blockIdx.x*2048 + t*8;
  int v[8]; int s = 0;
  #pragma unroll
  for (int u = 0; u < 8; u++){ int i = base+u; v[u] = (i < n) ? data[i] : 0; s += v[u]; }
  ws[t] = s; __syncthreads();
  for (int st = 1; st < 256; st <<= 1){
    int a = (t >= st) ? ws[t-st] : 0; __syncthreads();
    ws[t] += a; __syncthreads();
  }
  int off = blockoff + ws[t] - s;
  #pragma unroll
  for (int u = 0; u < 8; u++){
    int i = base+u;
    if (i < n){ data[i] = off; off += v[u]; }
  }
}

__global__ void k_escatter6(const int* __restrict__ keyin, const int* __restrict__ valin,
                            int* __restrict__ keyout, int* __restrict__ valout,
                            const int* __restrict__ hist, int shift){
  __shared__ int dbase[64], run[64], wcnt[4][64];
  int t = threadIdx.x, lane = t & 63, w = t >> 6;
  if (t < 64){ dbase[t] = hist[t*ENB + blockIdx.x]; run[t] = 0; }
  __syncthreads();
  for (int u = 0; u < 8; u++){
    if (t < 64){ wcnt[0][t]=0; wcnt[1][t]=0; wcnt[2][t]=0; wcnt[3][t]=0; }
    __syncthreads();
    int g = blockIdx.x*EB + u*256 + t;
    int kk = keyin[g], vv = valin[g];
    int d = (kk >> shift) & 63;
    unsigned long long m = ~0ull;
    #pragma unroll
    for (int b = 0; b < 6; b++){
      unsigned long long bal = __ballot((d >> b) & 1);
      m &= ((d >> b) & 1) ? bal : ~bal;
    }
    int rnk = __popcll(m & ((1ull << lane) - 1ull));
    if (rnk == 0) wcnt[w][d] = __popcll(m);
    __syncthreads();
    int off2 = run[d] + rnk;
    for (int w2 = 0; w2 < w; w2++) off2 += wcnt[w2][d];
    int pos = dbase[d] + off2;
    keyout[pos] = kk; valout[pos] = vv;
    __syncthreads();
    if (t < 64) run[t] += wcnt[0][t] + wcnt[1][t] + wcnt[2][t] + wcnt[3][t];
    __syncthreads();
  }
}

// ======================= per-bucket CSR build (LDS counting sort) =======================
// bucket b = dst in [b*2048,(b+1)*2048); edges for bucket b are contiguous in ek/ev.
// All col writes land in the bucket's own ~128KB window -> no write amplification.
__global__ __launch_bounds__(1024) void k_bucket_build(
    const int* __restrict__ ek, const int* __restrict__ ev,
    const int* __restrict__ hist_s,   // exclusive-scanned [64][ENB]
    int* __restrict__ rp, int* __restrict__ col,
    float* __restrict__ dA, float* __restrict__ dB, int n){
  __shared__ int cnt[2048];
  __shared__ int sa[1024], sb[1024];
  int b = blockIdx.x, t = threadIdx.x;
  int gb = hist_s[b*ENB];
  int ge = hist_s[(b+1)*ENB];
  int n0 = b*2048;
  cnt[t] = 0; cnt[t+1024] = 0;
  __syncthreads();
  for (int e = gb + t; e < ge; e += 1024)
    atomicAdd(&cnt[ek[e] - n0], 1);
  __syncthreads();
  int v0 = cnt[2*t], v1 = cnt[2*t+1];
  int s = v0 + v1;
  // inclusive scan of pair-sums over 1024 threads (ping-pong)
  sa[t] = s; __syncthreads();
  int* cu = sa; int* ot = sb;
  for (int st = 1; st < 1024; st <<= 1){
    ot[t] = cu[t] + ((t >= st) ? cu[t-st] : 0);
    __syncthreads();
    int* tmp = cu; cu = ot; ot = tmp;
  }
  int base2 = cu[t] - s;              // exclusive prefix
  int p0 = base2, p1 = base2 + v0;
  int nn = n - n0; if (nn > 2048) nn = 2048;
  cnt[2*t]   = gb + p0;               // repurpose as cursors
  cnt[2*t+1] = gb + p1;
  int i0 = n0 + 2*t;
  if (2*t < nn){
    rp[i0] = gb + p0;
    dA[i0] = 1.0f/sqrtf((float)v0 + 2.f);
    dB[i0] = 1.0f/sqrtf((float)v0 + 1.f);
  }
  if (2*t+1 < nn){
    rp[i0+1] = gb + p1;
    dA[i0+1] = 1.0f/sqrtf((float)v1 + 2.f);
    dB[i0+1] = 1.0f/sqrtf((float)v1 + 1.f);
  }
  if (b == (int)gridDim.x - 1 && t == 0) rp[n] = ge;
  __syncthreads();
  for (int e = gb + t; e < ge; e += 1024){
    int d = ek[e];
    int pos = atomicAdd(&cnt[d - n0], 1);
    col[pos] = ev[e];
  }
}

// ======================= fused single-dispatch scan (child CSR) =======================
__global__ void k_scan_rp(const int* __restrict__ in, int* __restrict__ rp,
                          int* __restrict__ cur, float* __restrict__ dA,
                          float* __restrict__ dB, int n){
  __shared__ int ws[256];
  int t = threadIdx.x;
  int pre = blockIdx.x*2048;
  int s = 0;
  for (int i = t; i < pre; i += 256) s += in[i];
  ws[t] = s; __syncthreads();
  for (int st = 128; st > 0; st >>= 1){
    if (t < st) ws[t] += ws[t+st];
    __syncthreads();
  }
  int blockoff = ws[0];
  __syncthreads();
  int base = pre + t*8;
  int v[8]; int ls = 0;
  #pragma unroll
  for (int u = 0; u < 8; u++){ int i = base+u; v[u] = (i < n) ? in[i] : 0; ls += v[u]; }
  ws[t] = ls; __syncthreads();
  for (int st = 1; st < 256; st <<= 1){
    int a = (t >= st) ? ws[t-st] : 0; __syncthreads();
    ws[t] += a; __syncthreads();
  }
  int off = blockoff + ws[t] - ls;
  #pragma unroll
  for (int u = 0; u < 8; u++){
    int i = base+u;
    if (i < n){
      rp[i] = off;
      if (cur) cur[i] = off;
      off += v[u];
      dA[i] = 1.0f/sqrtf((float)v[u] + 2.f);
      if (dB) dB[i] = 1.0f/sqrtf((float)v[u] + 1.f);
      if (i == n-1) rp[n] = off;
    }
  }
}

// ======================= convs (gather + matmul + BN partials) =======================
__global__ void k_conv64(const int* __restrict__ rp, const int* __restrict__ col,
                         const float* __restrict__ dinv, const float* __restrict__ x,
                         const float* __restrict__ W, float* __restrict__ out,
                         float* __restrict__ part, int n){
  __shared__ float yl[4][64];
  __shared__ float ls[64], lq[64];
  int lane = threadIdx.x & 63, w = threadIdx.x >> 6;
  if (threadIdx.x < 64){ ls[threadIdx.x] = 0.f; lq[threadIdx.x] = 0.f; }
  __syncthreads();
  float sa = 0.f, sq = 0.f;
  int wid = blockIdx.x*4 + w, nw = gridDim.x*4;
  for (int i = wid; i < n; i += nw){
    int beg = rp[i], end = rp[i+1];
    float di = dinv[i];
    float y = 0.f;
    int j = beg;
    for (; j + 4 <= end; j += 4){
      int s0 = col[j], s1 = col[j+1], s2 = col[j+2], s3 = col[j+3];
      float y0 = dinv[s0]*x[s0*64+lane];
      float y1 = dinv[s1]*x[s1*64+lane];
      float y2 = dinv[s2]*x[s2*64+lane];
      float y3 = dinv[s3]*x[s3*64+lane];
      y += (y0+y1) + (y2+y3);
    }
    for (; j < end; j++){ int s = col[j]; y += dinv[s]*x[s*64+lane]; }
    y = di*y + 2.f*di*di*x[i*64+lane];
    yl[w][lane] = y;
    float acc = 0.f;
    #pragma unroll
    for (int k2 = 0; k2 < 64; k2++)
      acc += yl[w][k2]*W[k2*64+lane];
    out[i*64+lane] = acc;
    sa += acc; sq += acc*acc;
  }
  atomicAdd(&ls[lane], sa); atomicAdd(&lq[lane], sq);
  __syncthreads();
  if (threadIdx.x < 128)
    part[blockIdx.x*128 + threadIdx.x] =
      (threadIdx.x < 64) ? ls[threadIdx.x] : lq[threadIdx.x-64];
}

__global__ void k_conv3(const int* __restrict__ rp, const int* __restrict__ col,
                        const float* __restrict__ dinv, const float* __restrict__ x,
                        const float* __restrict__ W, float* __restrict__ out,
                        float* __restrict__ part, int n){
  __shared__ float ls[64], lq[64];
  int lane = threadIdx.x & 63, w = threadIdx.x >> 6;
  if (threadIdx.x < 64){ ls[threadIdx.x] = 0.f; lq[threadIdx.x] = 0.f; }
  __syncthreads();
  float wf0 = W[lane], wf1 = W[64+lane], wf2 = W[128+lane];
  float sa = 0.f, sq = 0.f;
  int wid = blockIdx.x*4 + w, nw = gridDim.x*4;
  for (int i = wid; i < n; i += nw){
    int beg = rp[i], end = rp[i+1];
    float a0 = 0.f, a1 = 0.f, a2 = 0.f;
    for (int j = beg + lane; j < end; j += 64){
      int s2 = col[j];
      float ds = dinv[s2];
      a0 += ds*x[s2*3+0]; a1 += ds*x[s2*3+1]; a2 += ds*x[s2*3+2];
    }
    for (int o = 32; o > 0; o >>= 1){
      a0 += __shfl_xor(a0, o); a1 += __shfl_xor(a1, o); a2 += __shfl_xor(a2, o);
    }
    float di = dinv[i];
    float sl = 2.f*di*di;
    a0 = di*a0 + sl*x[i*3+0];
    a1 = di*a1 + sl*x[i*3+1];
    a2 = di*a2 + sl*x[i*3+2];
    float s = a0*wf0 + a1*wf1 + a2*wf2;
    out[i*64+lane] = s; sa += s; sq += s*s;
  }
  atomicAdd(&ls[lane], sa); atomicAdd(&lq[lane], sq);
  __syncthreads();
  if (threadIdx.x < 128)
    part[blockIdx.x*128 + threadIdx.x] =
      (threadIdx.x < 64) ? ls[threadIdx.x] : lq[threadIdx.x-64];
}

__global__ void k_stats_reduce(const float* __restrict__ part, float* __restrict__ stats){
  int c = blockIdx.x, lane = threadIdx.x;
  float s = 0.f;
  for (int b = lane; b < MMB_GRID; b += 64) s += part[b*128 + c];
  for (int o = 32; o > 0; o >>= 1) s += __shfl_xor(s, o);
  if (lane == 0) stats[c] = s;
}

// ======================= pool: BN+ReLU (in-place) + score + key init =================
__global__ void k_bnrelu_score(float* __restrict__ x, const float* __restrict__ stats,
                               const float* __restrict__ gamma, const float* __restrict__ beta,
                               const float* __restrict__ pw,
                               float* __restrict__ score, unsigned* __restrict__ key,
                               int* __restrict__ idx, int n, int P){
  int lane = threadIdx.x & 63, w = threadIdx.x >> 6;
  int wid = blockIdx.x*4 + w, nw = gridDim.x*4;
  float inv_n = 1.f/(float)n;
  float mu = stats[lane]*inv_n;
  float var = stats[64+lane]*inv_n - mu*mu;
  float gs = gamma[lane]*(1.f/sqrtf(var+1e-5f));
  float bt = beta[lane];
  float pv = pw[lane];
  float q = pv*pv;
  for (int o = 32; o > 0; o >>= 1) q += __shfl_xor(q, o);
  float qn = 1.f/sqrtf(q);
  for (int i = wid; i < n; i += nw){
    float v = fmaxf(gs*(x[i*64+lane]-mu)+bt, 0.f);
    x[i*64+lane] = v;
    float s = v*pv;
    for (int o = 32; o > 0; o >>= 1) s += __shfl_xor(s, o);
    if (lane == 0){
      float sc = fmaxf(s*qn, 0.f);
      score[i] = sc; key[i] = ~__float_as_uint(sc); idx[i] = i;
    }
  }
  for (int g = n + wid; g < P; g += nw)
    if (lane == 0){ key[g] = 0xFFFFFFFFu; idx[g] = 0; }
}

// ======================= score radix sort (LDS hist, stable, exact) =======================
__global__ void k_radix_hist(const unsigned* __restrict__ key, int* __restrict__ hist,
                             int shift, int nblk){
  __shared__ int lh[256];
  lh[threadIdx.x] = 0; __syncthreads();
  int base = blockIdx.x*1024 + threadIdx.x;
  #pragma unroll
  for (int u = 0; u < 4; u++){
    unsigned d = (key[base + u*256] >> shift) & 255u;
    atomicAdd(&lh[d], 1);
  }
  __syncthreads();
  hist[threadIdx.x*nblk + blockIdx.x] = lh[threadIdx.x];
}

__global__ void k_radix_scatter(const unsigned* __restrict__ keyin, const int* __restrict__ idxin,
                                unsigned* __restrict__ keyout, int* __restrict__ idxout,
                                const int* __restrict__ hist, int shift, int nblk){
  __shared__ int dbase[256], run[256], sc[256];
  __shared__ int wcnt[4][256];
  int t = threadIdx.x, lane = t & 63, w = t >> 6;
  int pre = 0, tot = 0;
  for (int b = 0; b < nblk; b++){
    int v = hist[t*nblk + b];
    if (b < blockIdx.x) pre += v;
    tot += v;
  }
  sc[t] = tot; __syncthreads();
  for (int st = 1; st < 256; st <<= 1){
    int a = (t >= st) ? sc[t-st] : 0; __syncthreads();
    sc[t] += a; __syncthreads();
  }
  dbase[t] = sc[t] - tot + pre;
  run[t] = 0;
  for (int u = 0; u < 4; u++){
    wcnt[0][t] = 0; wcnt[1][t] = 0; wcnt[2][t] = 0; wcnt[3][t] = 0;
    __syncthreads();
    int g = blockIdx.x*1024 + u*256 + t;
    unsigned kk = keyin[g]; int id = idxin[g];
    unsigned d = (kk >> shift) & 255u;
    unsigned long long m = ~0ull;
    #pragma unroll
    for (int b = 0; b < 8; b++){
      unsigned long long bal = __ballot((d >> b) & 1u);
      m &= ((d >> b) & 1u) ? bal : ~bal;
    }
    int rnk = __popcll(m & ((1ull << lane) - 1ull));
    if (rnk == 0) wcnt[w][d] = __popcll(m);
    __syncthreads();
    int off2 = run[d] + rnk;
    for (int w2 = 0; w2 < w; w2++) off2 += wcnt[w2][d];
    int pos = dbase[d] + off2;
    keyout[pos] = kk; idxout[pos] = id;
    __syncthreads();
    run[t] += wcnt[0][t] + wcnt[1][t] + wcnt[2][t] + wcnt[3][t];
    __syncthreads();
  }
}

// ======================= select + gather-scale =======================
__global__ void k_select_gather(const int* __restrict__ idxs, const float* __restrict__ x,
                                const float* __restrict__ score, int* __restrict__ perm,
                                int* __restrict__ mapv, float* __restrict__ xk, int n, int k){
  int t = blockIdx.x*blockDim.x + threadIdx.x;
  if (t < n){
    int i = idxs[t];
    mapv[i] = (t < k) ? t : -1;
    if (t < k) perm[t] = i;
  }
  if (t < k*64){
    int r = t >> 6, f = t & 63;
    int i = idxs[r];
    xk[t] = x[i*64+f]*score[i];
  }
}

// ======================= child CSR from parent CSR + injective mapping ================
__global__ void k_hist_mapped(const int* __restrict__ rp_p, const int* __restrict__ col_p,
                              const int* __restrict__ mapv, int* __restrict__ indeg, int np){
  int d = blockIdx.x*blockDim.x + threadIdx.x;
  if (d >= np) return;
  int md = mapv[d];
  if (md < 0) return;
  int c = 0, e = rp_p[d+1];
  int j = rp_p[d];
  for (; j + 4 <= e; j += 4){
    int c0 = (mapv[col_p[j]]   >= 0);
    int c1 = (mapv[col_p[j+1]] >= 0);
    int c2 = (mapv[col_p[j+2]] >= 0);
    int c3 = (mapv[col_p[j+3]] >= 0);
    c += (c0+c1) + (c2+c3);
  }
  for (; j < e; j++) if (mapv[col_p[j]] >= 0) c++;
  indeg[md] = c;
}

__global__ void k_scatter_mapped(const int* __restrict__ rp_p, const int* __restrict__ col_p,
                                 const int* __restrict__ mapv, const int* __restrict__ rp_c,
                                 int* __restrict__ col_c, int np){
  int d = blockIdx.x*blockDim.x + threadIdx.x;
  if (d >= np) return;
  int md = mapv[d];
  if (md < 0) return;
  int pos = rp_c[md], e = rp_p[d+1];
  int j = rp_p[d];
  for (; j + 4 <= e; j += 4){
    int m0 = mapv[col_p[j]], m1 = mapv[col_p[j+1]];
    int m2 = mapv[col_p[j+2]], m3 = mapv[col_p[j+3]];
    if (m0 >= 0) col_c[pos++] = m0;
    if (m1 >= 0) col_c[pos++] = m1;
    if (m2 >= 0) col_c[pos++] = m2;
    if (m3 >= 0) col_c[pos++] = m3;
  }
  for (; j < e; j++){
    int ms = mapv[col_p[j]];
    if (ms >= 0) col_c[pos++] = ms;
  }
}

// ======================= up-path BN+ReLU + scatter-add =======================
__global__ void k_bnrelu_scatter(const float* __restrict__ x, const float* __restrict__ stats,
                                 const float* __restrict__ gamma, const float* __restrict__ beta,
                                 const int* __restrict__ perm, float* __restrict__ res, int n){
  int t = blockIdx.x*blockDim.x + threadIdx.x;
  if (t >= n*64) return;
  int r = t >> 6, f = t & 63;
  float inv_n = 1.0f/(float)n;
  float mu = stats[f]*inv_n;
  float var = stats[64+f]*inv_n - mu*mu;
  float v = gamma[f]*(x[t]-mu)*(1.0f/sqrtf(var+1e-5f)) + beta[f];
  res[perm[r]*64+f] += fmaxf(v, 0.f);
}

// ======================= final conv =======================
__global__ void k_matvec(const float* __restrict__ x, const float* __restrict__ W,
                         float* __restrict__ h1, int n){
  int lane = threadIdx.x & 63, w = threadIdx.x >> 6;
  int wid = blockIdx.x*4 + w, nw = gridDim.x*4;
  float wv = W[lane];
  for (int i = wid; i < n; i += nw){
    float v = x[i*64+lane]*wv;
    for (int o = 32; o > 0; o >>= 1) v += __shfl_xor(v, o);
    if (lane == 0) h1[i] = v;
  }
}

__global__ void k_gather_sig(const int* __restrict__ rp, const int* __restrict__ col,
                             const float* __restrict__ dinv, const float* __restrict__ h1,
                             float* __restrict__ out, int n){
  int i = blockIdx.x*blockDim.x + threadIdx.x;
  if (i >= n) return;
  int beg = rp[i], end = rp[i+1];
  float di = dinv[i];
  float acc = 0.f;
  int j = beg;
  for (; j + 4 <= end; j += 4){
    int s0 = col[j], s1 = col[j+1], s2 = col[j+2], s3 = col[j+3];
    float v0 = dinv[s0]*h1[s0];
    float v1 = dinv[s1]*h1[s1];
    float v2 = dinv[s2]*h1[s2];
    float v3 = dinv[s3]*h1[s3];
    acc += (v0+v1) + (v2+v3);
  }
  for (; j < end; j++) acc += dinv[col[j]]*h1[col[j]];
  float v = di*acc + di*di*h1[i];
  out[i] = 1.f/(1.f+expf(-v));
}

// ======================= host =======================

extern "C" void kernel_launch(void* const* d_in, const int* in_sizes, int n_in,
                              void* d_out, int out_size, void* d_ws, size_t ws_size,
                              hipStream_t stream) {
  const float* x_in = (const float*)d_in[0];
  const int* ei = (const int*)d_in[1];
  const int* src0 = ei;
  const int* dst0 = ei + NE;
  const float* W_d[4] = {(const float*)d_in[2],(const float*)d_in[5],(const float*)d_in[8],(const float*)d_in[11]};
  const float* g_d[4] = {(const float*)d_in[3],(const float*)d_in[6],(const float*)d_in[9],(const float*)d_in[12]};
  const float* b_d[4] = {(const float*)d_in[4],(const float*)d_in[7],(const float*)d_in[10],(const float*)d_in[13]};
  const float* pw[3]  = {(const float*)d_in[14],(const float*)d_in[15],(const float*)d_in[16]};
  const float* W_u[2] = {(const float*)d_in[17],(const float*)d_in[20]};
  const float* g_u[2] = {(const float*)d_in[18],(const float*)d_in[21]};
  const float* b_u[2] = {(const float*)d_in[19],(const float*)d_in[22]};
  const float* W_out  = (const float*)d_in[23];
  float* out = (float*)d_out;

  float* base = (float*)d_ws;
  size_t off = 0;
  auto alloc = [&](size_t nf){ float* p = base + off; off += nf; return p; };
  float* x0 = alloc(5120000);
  float* x1 = alloc(2560000);
  float* x2 = alloc(1280000);
  float* x3 = alloc(640000);
  float* A  = alloc(2560000);
  int* col0 = (int*)alloc(NE);
  int* col1 = (int*)alloc(NE);
  int* col2 = (int*)alloc(NE);
  int* col3 = (int*)alloc(NE);
  int* ek1 = (int*)alloc(NE);
  int* ev1 = (int*)alloc(NE);
  int* rp0 = (int*)alloc(80001);
  int* rp1 = (int*)alloc(40001);
  int* rp2 = (int*)alloc(20001);
  int* rp3 = (int*)alloc(10001);
  int* indeg  = (int*)alloc(NN0);
  float* dinv0  = alloc(NN0);
  float* dinv0f = alloc(NN0);
  float* dinv1  = alloc(40000);
  float* dinv2  = alloc(20000);
  float* dinv3  = alloc(10000);
  float* score = alloc(NN0);
  int* mapv = (int*)alloc(NN0);
  int* p0 = (int*)alloc(40000);
  int* p1 = (int*)alloc(20000);
  int* p2 = (int*)alloc(10000);
  float* stats = alloc(128);
  float* part  = alloc(MMB_GRID*128);
  unsigned* keyA = (unsigned*)alloc(81920);
  unsigned* keyB = (unsigned*)alloc(81920);
  int* idxA = (int*)alloc(81920);
  int* idxB = (int*)alloc(81920);
  int* hist = (int*)alloc(81920);
  int* ehist = (int*)alloc(64*ENB);
  int* bsum = (int*)alloc(256);
  (void)ws_size; (void)in_sizes; (void)n_in; (void)out_size;

  const int B = 256;

  // ---- level-0 CSR: single 6-bit bucket pass (shift=11) + per-bucket LDS build ----
  k_ehist6<<<ENB, B, 0, stream>>>(dst0, ehist, 11);
  {
    int nb = cdiv(64*ENB, 2048);
    k_scan_part    <<<nb, B, 0, stream>>>(ehist, bsum, 64*ENB);
    k_scan_fin_flat<<<nb, B, 0, stream>>>(ehist, bsum, nb, 64*ENB);
  }
  k_escatter6<<<ENB, B, 0, stream>>>(dst0, src0, ek1, ev1, ehist, 11);
  k_bucket_build<<<cdiv(NN0,2048), 1024, 0, stream>>>(ek1, ev1, ehist, rp0, col0,
                                                      dinv0, dinv0f, NN0);

  auto conv = [&](const float* xin, const float* W, int n,
                  const int* rp, const int* col, const float* dv, float* dstb){
    k_conv64<<<MMB_GRID, B, 0, stream>>>(rp, col, dv, xin, W, dstb, part, n);
    k_stats_reduce<<<128, 64, 0, stream>>>(part, stats);
  };

  auto pool = [&](float* xb, const float* gm, const float* bt, const float* pwv,
                  int n, int k, int* pm){
    int nblk = cdiv(n, 1024), P = nblk*1024;
    k_bnrelu_score<<<1024, B, 0, stream>>>(xb, stats, gm, bt, pwv, score, keyA, idxA, n, P);
    unsigned* ka = keyA; int* ia = idxA; unsigned* kb = keyB; int* ib = idxB;
    for (int pass = 0; pass < 4; pass++){
      k_radix_hist   <<<nblk, B, 0, stream>>>(ka, hist, pass*8, nblk);
      k_radix_scatter<<<nblk, B, 0, stream>>>(ka, ia, kb, ib, hist, pass*8, nblk);
      unsigned* tk = ka; ka = kb; kb = tk;
      int* ti = ia; ia = ib; ib = ti;
    }
    k_select_gather<<<cdiv(k*64,B), B, 0, stream>>>(ia, xb, score, pm, mapv, A, n, k);
  };

  auto csr_mapped = [&](const int* rp_p, const int* col_p, int np, int nc,
                        int* rp_c, int* col_c, float* dv){
    k_hist_mapped<<<cdiv(np,B), B, 0, stream>>>(rp_p, col_p, mapv, indeg, np);
    k_scan_rp<<<cdiv(nc,2048), B, 0, stream>>>(indeg, rp_c, nullptr, dv, nullptr, nc);
    k_scatter_mapped<<<cdiv(np,B), B, 0, stream>>>(rp_p, col_p, mapv, rp_c, col_c, np);
  };

  // ---- down path ----
  k_conv3<<<MMB_GRID, B, 0, stream>>>(rp0, col0, dinv0, x_in, W_d[0], x0, part, NN0);
  k_stats_reduce<<<128, 64, 0, stream>>>(part, stats);
  pool(x0, g_d[0], b_d[0], pw[0], NN0, 40000, p0);
  csr_mapped(rp0, col0, NN0, 40000, rp1, col1, dinv1);

  conv(A, W_d[1], 40000, rp1, col1, dinv1, x1);
  pool(x1, g_d[1], b_d[1], pw[1], 40000, 20000, p1);
  csr_mapped(rp1, col1, 40000, 20000, rp2, col2, dinv2);

  conv(A, W_d[2], 20000, rp2, col2, dinv2, x2);
  pool(x2, g_d[2], b_d[2], pw[2], 20000, 10000, p2);
  csr_mapped(rp2, col2, 20000, 10000, rp3, col3, dinv3);

  conv(A, W_d[3], 10000, rp3, col3, dinv3, x3);

  // ---- up path (BN+ReLU fused into the skip-connection scatter-add) ----
  k_bnrelu_scatter<<<cdiv(10000*64,B), B, 0, stream>>>(x3, stats, g_d[3], b_d[3], p2, x2, 10000);
  conv(x2, W_u[0], 20000, rp2, col2, dinv2, A);
  k_bnrelu_scatter<<<cdiv(20000*64,B), B, 0, stream>>>(A, stats, g_u[0], b_u[0], p1, x1, 20000);
  conv(x1, W_u[1], 40000, rp1, col1, dinv1, A);
  k_bnrelu_scatter<<<cdiv(40000*64,B), B, 0, stream>>>(A, stats, g_u[1], b_u[1], p0, x0, 40000);

  // ---- final conv (fill = 1.0) fused with sigmoid ----
  float* h1 = score;  // reuse
  k_matvec<<<512, B, 0, stream>>>(x0, W_out, h1, NN0);
  k_gather_sig<<<cdiv(NN0,B), B, 0, stream>>>(rp0, col0, dinv0f, h1, out, NN0);
}